// Round 2
// baseline (616.843 us; speedup 1.0000x reference)
//
#include <hip/hip_runtime.h>
#include <stdint.h>
#include <stddef.h>

typedef __attribute__((ext_vector_type(8))) short bf16x8;
typedef __attribute__((ext_vector_type(4))) float f32x4;
typedef __attribute__((ext_vector_type(4))) unsigned int uint4v;

static __device__ __forceinline__ unsigned short f2bf(float f) {
  unsigned int u = __builtin_bit_cast(unsigned int, f);
  unsigned int r = (u + 0x7FFFu + ((u >> 16) & 1u)) >> 16;
  return (unsigned short)r;
}

static __device__ __forceinline__ void gld16(const void* g, void* l) {
  __builtin_amdgcn_global_load_lds(
      (const __attribute__((address_space(1))) void*)g,
      (__attribute__((address_space(3))) void*)l, 16, 0, 0);
}

// ---------- weight transpose + cast: src [R][C] f32 -> dst [C][R] bf16 ----------
__global__ void transpose_cast(const float* __restrict__ src,
                               unsigned short* __restrict__ dst, int R, int C) {
  __shared__ float tile[32][33];
  int c0 = blockIdx.x * 32, r0 = blockIdx.y * 32;
  int tx = threadIdx.x, ty = threadIdx.y;  // (32, 8)
  #pragma unroll
  for (int i = 0; i < 32; i += 8)
    tile[ty + i][tx] = src[(size_t)(r0 + ty + i) * C + c0 + tx];
  __syncthreads();
  #pragma unroll
  for (int i = 0; i < 32; i += 8)
    dst[(size_t)(c0 + ty + i) * R + r0 + tx] = f2bf(tile[tx][ty + i]);
}

// ---------- block reduce ----------
static __device__ __forceinline__ float blksum256(float v, float* sb) {
  #pragma unroll
  for (int o = 32; o > 0; o >>= 1) v += __shfl_down(v, o, 64);
  int lane = threadIdx.x & 63, w = threadIdx.x >> 6;
  __syncthreads();
  if (lane == 0) sb[w] = v;
  __syncthreads();
  return sb[0] + sb[1] + sb[2] + sb[3];
}

// ---------- LayerNorm (MODE 0: write shifted/window-partitioned rows; MODE 1: identity) ----------
template <int MODE>
__global__ __launch_bounds__(256) void ln_kernel(const float* __restrict__ x,
                                                 const float* __restrict__ gg,
                                                 const float* __restrict__ bb,
                                                 unsigned short* __restrict__ out) {
  __shared__ float sb[4];
  const int d = blockIdx.x;  // dest row (window order for MODE 0)
  size_t srow;
  if (MODE == 0) {
    int b = d >> 7, wid = (d >> 4) & 7, tok = d & 15;
    int oh = (((wid >> 2) << 2) + (tok >> 2) + 2) & 7;
    int ow = (((wid & 3) << 2) + (tok & 3) + 2) & 15;
    srow = (size_t)(b << 7) + oh * 16 + ow;
  } else {
    srow = d;
  }
  const float* xr = x + srow * 768;
  const int t = threadIdx.x;
  float v0 = xr[t], v1 = xr[t + 256], v2 = xr[t + 512];
  float mean = blksum256(v0 + v1 + v2, sb) * (1.0f / 768.0f);
  float d0 = v0 - mean, d1 = v1 - mean, d2 = v2 - mean;
  float var = blksum256(d0 * d0 + d1 * d1 + d2 * d2, sb) * (1.0f / 768.0f);
  float rstd = rsqrtf(var + 1e-5f);
  size_t o = (size_t)d * 768;
  out[o + t]       = f2bf(d0 * rstd * gg[t] + bb[t]);
  out[o + t + 256] = f2bf(d1 * rstd * gg[t + 256] + bb[t + 256]);
  out[o + t + 512] = f2bf(d2 * rstd * gg[t + 512] + bb[t + 512]);
}

// ---------- 256x256 8-wave phased GEMM: C[M][N] = A[M][K] @ BT[N][K]^T + bias ----------
// EPI 0: +bias -> bf16 (qkv)
// EPI 1: +bias, window-reverse+unshift scatter, +resid(x) -> fp32 xr (proj)
// EPI 2: +bias, exact gelu -> bf16 (fc1)
// EPI 3: +bias, +resid(xr) -> fp32 out (fc2)
template <int EPI>
__global__ __launch_bounds__(512, 2) void gemm256(
    const unsigned short* __restrict__ A, const unsigned short* __restrict__ BT,
    const float* __restrict__ bias, float* __restrict__ outF,
    unsigned short* __restrict__ outB, const float* __restrict__ resid,
    int M, int N, int K, int NT) {
  // [2 dbuf][256 rows][64 K] bf16, row stride 128B, 16B-granule swizzled by row&7
  __shared__ __align__(16) unsigned short sA[2][256 * 64];
  __shared__ __align__(16) unsigned short sB[2][256 * 64];

  const int tid = threadIdx.x;
  const int lane = tid & 63, wv = tid >> 6;
  const int wr = wv >> 2, wc = wv & 3;        // 2 (M) x 4 (N) wave grid
  const int fr = lane & 15, q4 = (lane >> 4) << 2;

  // bijective XCD swizzle (grid % 8 == 0 for all our launches)
  const int nwg = gridDim.x;
  const int orig = blockIdx.x;
  const int swz = (orig & 7) * (nwg >> 3) + (orig >> 3);
  const int mt = swz / NT, nt = swz - mt * NT;
  const int m0 = mt << 8, n0 = nt << 8;

  const size_t K2 = (size_t)K * 2;

  // staging: linear LDS dest (wave-uniform base + lane*16); pre-swizzled global src
  const int srow = tid >> 3;                  // row within 64-row issue group
  const int sg = tid & 7;                     // dest granule
  const int sgs = ((sg ^ (srow & 7)) << 4);   // swizzled source byte offset
  const char* pA = (const char*)A + (size_t)(m0 + srow) * K2 + sgs;
  const char* pB = (const char*)BT + (size_t)(n0 + srow) * K2 + sgs;
  char* lwA[2] = {(char*)&sA[0][0] + (wv << 10), (char*)&sA[1][0] + (wv << 10)};
  char* lwB[2] = {(char*)&sB[0][0] + (wv << 10), (char*)&sB[1][0] + (wv << 10)};

  // swizzled ds_read granule byte offsets per k-slice
  const int g0 = (((lane >> 4) ^ (fr & 7)) << 4);
  const int g1 = (((4 + (lane >> 4)) ^ (fr & 7)) << 4);
  const int arow = (wr << 7) + fr;
  const int brow = (wc << 6) + fr;

  f32x4 acc[8][4];
  #pragma unroll
  for (int i = 0; i < 8; ++i)
    #pragma unroll
    for (int j = 0; j < 4; ++j) acc[i][j] = (f32x4){0.f, 0.f, 0.f, 0.f};

  bf16x8 af[4][2], bb[2][2];
  const int KT = K >> 6;

#define STAGE(la, lb, t)                                                   \
  {                                                                        \
    const size_t koff = (size_t)(t) << 7;                                  \
    _Pragma("unroll") for (int j = 0; j < 4; ++j) {                        \
      gld16(pA + (size_t)(j * 64) * K2 + koff, (la) + j * 8192);           \
      gld16(pB + (size_t)(j * 64) * K2 + koff, (lb) + j * 8192);           \
    }                                                                      \
  }

#define LDA(cbuf, mh)                                                      \
  {                                                                        \
    const char* bas = (const char*)&sA[cbuf][0];                           \
    _Pragma("unroll") for (int fm = 0; fm < 4; ++fm) {                     \
      const int r = arow + (mh) * 64 + fm * 16;                            \
      af[fm][0] = *(const bf16x8*)(bas + r * 128 + g0);                    \
      af[fm][1] = *(const bf16x8*)(bas + r * 128 + g1);                    \
    }                                                                      \
  }

#define LDB(cbuf, nh)                                                      \
  {                                                                        \
    const char* bas = (const char*)&sB[cbuf][0];                           \
    _Pragma("unroll") for (int fn = 0; fn < 2; ++fn) {                     \
      const int r = brow + (nh) * 32 + fn * 16;                            \
      bb[fn][0] = *(const bf16x8*)(bas + r * 128 + g0);                    \
      bb[fn][1] = *(const bf16x8*)(bas + r * 128 + g1);                    \
    }                                                                      \
  }

#define MMA(mh, nh)                                                        \
  {                                                                        \
    __builtin_amdgcn_s_barrier();                                          \
    __builtin_amdgcn_s_setprio(1);                                         \
    _Pragma("unroll") for (int fm = 0; fm < 4; ++fm) {                     \
      _Pragma("unroll") for (int fn = 0; fn < 2; ++fn) {                   \
        acc[(mh)*4 + fm][(nh)*2 + fn] =                                    \
            __builtin_amdgcn_mfma_f32_16x16x32_bf16(                       \
                af[fm][0], bb[fn][0], acc[(mh)*4 + fm][(nh)*2 + fn], 0, 0, 0); \
        acc[(mh)*4 + fm][(nh)*2 + fn] =                                    \
            __builtin_amdgcn_mfma_f32_16x16x32_bf16(                       \
                af[fm][1], bb[fn][1], acc[(mh)*4 + fm][(nh)*2 + fn], 0, 0, 0); \
      }                                                                    \
    }                                                                      \
    __builtin_amdgcn_s_setprio(0);                                         \
    __builtin_amdgcn_s_barrier();                                          \
  }

  // prologue: stage tiles 0 and 1
  STAGE(lwA[0], lwB[0], 0);
  STAGE(lwA[1], lwB[1], 1);
  asm volatile("s_waitcnt vmcnt(8)" ::: "memory");
  __builtin_amdgcn_s_barrier();

  for (int t = 0; t < KT; ++t) {
    const int cur = t & 1;
    LDA(cur, 0) LDB(cur, 0) MMA(0, 0)
    LDB(cur, 1) MMA(0, 1)
    LDA(cur, 1) MMA(1, 1)
    LDB(cur, 0) MMA(1, 0)
    if (t + 2 < KT) {
      STAGE(lwA[cur], lwB[cur], t + 2);
      asm volatile("s_waitcnt vmcnt(8)" ::: "memory");
    } else {
      asm volatile("s_waitcnt vmcnt(0)" ::: "memory");
    }
    __builtin_amdgcn_s_barrier();
  }
#undef STAGE
#undef LDA
#undef LDB
#undef MMA

  #pragma unroll
  for (int ai = 0; ai < 8; ++ai) {
    #pragma unroll
    for (int bj = 0; bj < 4; ++bj) {
      const int col = n0 + (wc << 6) + bj * 16 + fr;
      const float bc = bias[col];
      #pragma unroll
      for (int i = 0; i < 4; ++i) {
        const int row = m0 + (wr << 7) + ai * 16 + q4 + i;
        float v = acc[ai][bj][i] + bc;
        if (EPI == 0) {
          outB[(size_t)row * N + col] = f2bf(v);
        } else if (EPI == 1) {
          int b = row >> 7, wid = (row >> 4) & 7, tok = row & 15;
          int oh = (((wid >> 2) << 2) + (tok >> 2) + 2) & 7;
          int ow = (((wid & 3) << 2) + (tok & 3) + 2) & 15;
          size_t di = ((size_t)(b << 7) + oh * 16 + ow) * 768 + col;
          outF[di] = v + resid[di];
        } else if (EPI == 2) {
          float g = 0.5f * v * (1.0f + erff(v * 0.70710678118f));
          outB[(size_t)row * N + col] = f2bf(g);
        } else {
          size_t di = (size_t)row * N + col;
          outF[di] = v + resid[di];
        }
      }
    }
  }
}

// ---------- window attention: one wave per (window, head) ----------
__global__ __launch_bounds__(64) void attn_win(const unsigned short* __restrict__ qkv,
                                               const float* __restrict__ rel_table,
                                               unsigned short* __restrict__ o) {
  __shared__ __align__(16) unsigned short q_s[16 * 64];
  __shared__ __align__(16) unsigned short k_s[16 * 64];
  __shared__ __align__(16) unsigned short vt_s[64 * 32];  // [d][m], m padded to 32
  __shared__ __align__(16) unsigned short p_s[16 * 32];   // [n][m], m padded to 32
  const int bid = blockIdx.x;
  const int win = bid / 12;
  const int head = bid - win * 12;
  const int wid = win & 7;
  const int lane = threadIdx.x;
  const unsigned short* gq =
      qkv + (size_t)win * 16 * 2304 + head * 64 + (size_t)(lane >> 2) * 2304 + ((lane & 3) << 4);
  const int t = lane >> 2, d0 = (lane & 3) << 4;
  *(uint4v*)&q_s[t * 64 + d0]     = *(const uint4v*)(gq);
  *(uint4v*)&q_s[t * 64 + d0 + 8] = *(const uint4v*)(gq + 8);
  *(uint4v*)&k_s[t * 64 + d0]     = *(const uint4v*)(gq + 768);
  *(uint4v*)&k_s[t * 64 + d0 + 8] = *(const uint4v*)(gq + 776);
  unsigned short vv[16];
  *(uint4v*)&vv[0] = *(const uint4v*)(gq + 1536);
  *(uint4v*)&vv[8] = *(const uint4v*)(gq + 1544);
  #pragma unroll
  for (int e = 0; e < 16; ++e) vt_s[(d0 + e) * 32 + t] = vv[e];
  #pragma unroll
  for (int e = 0; e < 16; ++e) vt_s[lane * 32 + 16 + e] = 0;  // K-pad of V
  if (lane < 16) {
    #pragma unroll
    for (int e = 0; e < 16; ++e) p_s[lane * 32 + 16 + e] = 0;  // K-pad of P
  }
  __syncthreads();

  const int fr = lane & 15, kg = (lane >> 4) << 3;
  bf16x8 qa0 = *(const bf16x8*)&q_s[fr * 64 + kg];
  bf16x8 qa1 = *(const bf16x8*)&q_s[fr * 64 + 32 + kg];
  bf16x8 ka0 = *(const bf16x8*)&k_s[fr * 64 + kg];
  bf16x8 ka1 = *(const bf16x8*)&k_s[fr * 64 + 32 + kg];
  f32x4 s = (f32x4){0.f, 0.f, 0.f, 0.f};
  s = __builtin_amdgcn_mfma_f32_16x16x32_bf16(qa0, ka0, s, 0, 0, 0);
  s = __builtin_amdgcn_mfma_f32_16x16x32_bf16(qa1, ka1, s, 0, 0, 0);
  // S[n][m]: n = (lane>>4)*4 + i, m = fr

  const int wh = wid >> 2, wwc = wid & 3;
  const int rj = fr >> 2, cj = fr & 3;
  const int rowm = wh * 4 + rj, colm = wwc * 4 + cj;
  const int rgm = (rowm < 4 ? 0 : (rowm < 6 ? 1 : 2)) * 3 +
                  (colm < 12 ? 0 : (colm < 14 ? 1 : 2));
  float p[4];
  #pragma unroll
  for (int i = 0; i < 4; ++i) {
    int n = ((lane >> 4) << 2) + i;
    int ri = n >> 2, ci = n & 3;
    int rown = wh * 4 + ri, coln = wwc * 4 + ci;
    int rgn = (rown < 4 ? 0 : (rown < 6 ? 1 : 2)) * 3 +
              (coln < 12 ? 0 : (coln < 14 ? 1 : 2));
    float bias = rel_table[(size_t)((ri - rj + 3) * 7 + (ci - cj + 3)) * 12 + head];
    p[i] = s[i] * 0.125f + bias + (rgn != rgm ? -100.0f : 0.0f);
  }
  float mx[4] = {p[0], p[1], p[2], p[3]};
  #pragma unroll
  for (int off = 8; off > 0; off >>= 1)
    #pragma unroll
    for (int i = 0; i < 4; ++i) mx[i] = fmaxf(mx[i], __shfl_xor(mx[i], off, 64));
  float sm[4];
  #pragma unroll
  for (int i = 0; i < 4; ++i) { p[i] = __expf(p[i] - mx[i]); sm[i] = p[i]; }
  #pragma unroll
  for (int off = 8; off > 0; off >>= 1)
    #pragma unroll
    for (int i = 0; i < 4; ++i) sm[i] += __shfl_xor(sm[i], off, 64);
  #pragma unroll
  for (int i = 0; i < 4; ++i)
    p_s[(((lane >> 4) << 2) + i) * 32 + fr] = f2bf(p[i] / sm[i]);
  __syncthreads();

  bf16x8 pa = *(const bf16x8*)&p_s[fr * 32 + kg];
  const f32x4 oz = (f32x4){0.f, 0.f, 0.f, 0.f};
  #pragma unroll
  for (int c = 0; c < 4; ++c) {
    bf16x8 vb = *(const bf16x8*)&vt_s[(c * 16 + fr) * 32 + kg];
    f32x4 oa = __builtin_amdgcn_mfma_f32_16x16x32_bf16(pa, vb, oz, 0, 0, 0);
    #pragma unroll
    for (int i = 0; i < 4; ++i) {
      int n = ((lane >> 4) << 2) + i;
      o[((size_t)win * 16 + n) * 768 + head * 64 + c * 16 + fr] = f2bf(oa[i]);
    }
  }
}

extern "C" void kernel_launch(void* const* d_in, const int* in_sizes, int n_in,
                              void* d_out, int out_size, void* d_ws, size_t ws_size,
                              hipStream_t stream) {
  const float* x      = (const float*)d_in[0];
  const float* ln1_g  = (const float*)d_in[1];
  const float* ln1_b  = (const float*)d_in[2];
  const float* qkv_w  = (const float*)d_in[3];
  const float* qkv_b  = (const float*)d_in[4];
  const float* proj_w = (const float*)d_in[5];
  const float* proj_b = (const float*)d_in[6];
  const float* rel_t  = (const float*)d_in[7];
  const float* ln2_g  = (const float*)d_in[8];
  const float* ln2_b  = (const float*)d_in[9];
  const float* fc1_w  = (const float*)d_in[10];
  const float* fc1_b  = (const float*)d_in[11];
  const float* fc2_w  = (const float*)d_in[12];
  const float* fc2_b  = (const float*)d_in[13];
  float* out = (float*)d_out;

  char* ws = (char*)d_ws;
  // region A (50,331,648 B): hw -> o -> y  (all [32768][768] bf16, sequential reuse)
  unsigned short* wsA = (unsigned short*)(ws);
  // region B: qkv bf16 [32768][2304]; later xr fp32 [32768][768]
  unsigned short* qkvb = (unsigned short*)(ws + 50331648);
  float* xr = (float*)(ws + 50331648);
  // region C: h1 bf16 [32768][1024]
  unsigned short* h1 = (unsigned short*)(ws + 201326592);
  // bf16 transposed weights
  unsigned short* qkv_wT = (unsigned short*)(ws + 268435456);  // [2304][768]
  unsigned short* proj_wT = (unsigned short*)(ws + 271974400); // [768][768]
  unsigned short* fc1_wT = (unsigned short*)(ws + 273154048);  // [1024][768]
  unsigned short* fc2_wT = (unsigned short*)(ws + 274726912);  // [768][1024]

  dim3 tb(32, 8);
  transpose_cast<<<dim3(2304 / 32, 768 / 32), tb, 0, stream>>>(qkv_w, qkv_wT, 768, 2304);
  transpose_cast<<<dim3(768 / 32, 768 / 32), tb, 0, stream>>>(proj_w, proj_wT, 768, 768);
  transpose_cast<<<dim3(1024 / 32, 768 / 32), tb, 0, stream>>>(fc1_w, fc1_wT, 768, 1024);
  transpose_cast<<<dim3(768 / 32, 1024 / 32), tb, 0, stream>>>(fc2_w, fc2_wT, 1024, 768);

  ln_kernel<0><<<32768, 256, 0, stream>>>(x, ln1_g, ln1_b, wsA);                 // hw
  gemm256<0><<<dim3(128 * 9), 512, 0, stream>>>(wsA, qkv_wT, qkv_b, nullptr, qkvb,
                                                nullptr, 32768, 2304, 768, 9);   // qkv
  attn_win<<<24576, 64, 0, stream>>>(qkvb, rel_t, wsA);                          // o
  gemm256<1><<<dim3(128 * 3), 512, 0, stream>>>(wsA, proj_wT, proj_b, xr, nullptr,
                                                x, 32768, 768, 768, 3);          // xr = x + proj(o)
  ln_kernel<1><<<32768, 256, 0, stream>>>(xr, ln2_g, ln2_b, wsA);                // y
  gemm256<2><<<dim3(128 * 4), 512, 0, stream>>>(wsA, fc1_wT, fc1_b, nullptr, h1,
                                                nullptr, 32768, 1024, 768, 4);   // h1 = gelu(...)
  gemm256<3><<<dim3(128 * 3), 512, 0, stream>>>(h1, fc2_wT, fc2_b, out, nullptr,
                                                xr, 32768, 768, 1024, 3);        // out = xr + fc2(h1)
}

// Round 3
// 580.382 us; speedup vs baseline: 1.0628x; 1.0628x over previous
//
#include <hip/hip_runtime.h>
#include <stdint.h>
#include <stddef.h>

typedef __attribute__((ext_vector_type(8))) short bf16x8;
typedef __attribute__((ext_vector_type(4))) float f32x4;
typedef __attribute__((ext_vector_type(4))) unsigned int uint4v;

static __device__ __forceinline__ unsigned short f2bf(float f) {
  unsigned int u = __builtin_bit_cast(unsigned int, f);
  unsigned int r = (u + 0x7FFFu + ((u >> 16) & 1u)) >> 16;
  return (unsigned short)r;
}

static __device__ __forceinline__ void gld16(const void* g, void* l) {
  __builtin_amdgcn_global_load_lds(
      (const __attribute__((address_space(1))) void*)g,
      (__attribute__((address_space(3))) void*)l, 16, 0, 0);
}

// ---------- weight transpose + cast: src [R][C] f32 -> dst [C][R] bf16 ----------
__global__ void transpose_cast(const float* __restrict__ src,
                               unsigned short* __restrict__ dst, int R, int C) {
  __shared__ float tile[32][33];
  int c0 = blockIdx.x * 32, r0 = blockIdx.y * 32;
  int tx = threadIdx.x, ty = threadIdx.y;  // (32, 8)
  #pragma unroll
  for (int i = 0; i < 32; i += 8)
    tile[ty + i][tx] = src[(size_t)(r0 + ty + i) * C + c0 + tx];
  __syncthreads();
  #pragma unroll
  for (int i = 0; i < 32; i += 8)
    dst[(size_t)(c0 + ty + i) * R + r0 + tx] = f2bf(tile[tx][ty + i]);
}

// ---------- block reduce ----------
static __device__ __forceinline__ float blksum256(float v, float* sb) {
  #pragma unroll
  for (int o = 32; o > 0; o >>= 1) v += __shfl_down(v, o, 64);
  int lane = threadIdx.x & 63, w = threadIdx.x >> 6;
  __syncthreads();
  if (lane == 0) sb[w] = v;
  __syncthreads();
  return sb[0] + sb[1] + sb[2] + sb[3];
}

// ---------- LayerNorm (MODE 0: write shifted/window-partitioned rows; MODE 1: identity) ----------
template <int MODE>
__global__ __launch_bounds__(256) void ln_kernel(const float* __restrict__ x,
                                                 const float* __restrict__ gg,
                                                 const float* __restrict__ bb,
                                                 unsigned short* __restrict__ out) {
  __shared__ float sb[4];
  const int d = blockIdx.x;  // dest row (window order for MODE 0)
  size_t srow;
  if (MODE == 0) {
    int b = d >> 7, wid = (d >> 4) & 7, tok = d & 15;
    int oh = (((wid >> 2) << 2) + (tok >> 2) + 2) & 7;
    int ow = (((wid & 3) << 2) + (tok & 3) + 2) & 15;
    srow = (size_t)(b << 7) + oh * 16 + ow;
  } else {
    srow = d;
  }
  const float* xr = x + srow * 768;
  const int t = threadIdx.x;
  float v0 = xr[t], v1 = xr[t + 256], v2 = xr[t + 512];
  float mean = blksum256(v0 + v1 + v2, sb) * (1.0f / 768.0f);
  float d0 = v0 - mean, d1 = v1 - mean, d2 = v2 - mean;
  float var = blksum256(d0 * d0 + d1 * d1 + d2 * d2, sb) * (1.0f / 768.0f);
  float rstd = rsqrtf(var + 1e-5f);
  size_t o = (size_t)d * 768;
  out[o + t]       = f2bf(d0 * rstd * gg[t] + bb[t]);
  out[o + t + 256] = f2bf(d1 * rstd * gg[t + 256] + bb[t + 256]);
  out[o + t + 512] = f2bf(d2 * rstd * gg[t + 512] + bb[t + 512]);
}

// ---------- 256x256 8-wave 8-phase GEMM (m201 schedule): C = A @ BT^T + bias ----------
// EPI 0: +bias -> bf16 (qkv)
// EPI 1: +bias, window-reverse+unshift scatter, +resid(x) -> fp32 xr (proj)
// EPI 2: +bias, exact gelu -> bf16 (fc1)
// EPI 3: +bias, +resid(xr) -> fp32 out (fc2)
template <int EPI>
__global__ __launch_bounds__(512, 2) void gemm256(
    const unsigned short* __restrict__ A, const unsigned short* __restrict__ BT,
    const float* __restrict__ bias, float* __restrict__ outF,
    unsigned short* __restrict__ outB, const float* __restrict__ resid,
    int M, int N, int K, int NT) {
  // per K-tile buffer: 256 rows x 64 K bf16, row stride 128B, 16B-granule swizzled by row&7
  // even K-tiles -> buf 0, odd -> buf 1 (static parity, no runtime indexing)
  __shared__ __align__(16) unsigned short sA[2][256 * 64];
  __shared__ __align__(16) unsigned short sB[2][256 * 64];

  const int tid = threadIdx.x;
  const int lane = tid & 63, wv = tid >> 6;
  const int wr = wv >> 2, wc = wv & 3;        // 2 (M) x 4 (N) wave grid
  const int fr = lane & 15, q4 = (lane >> 4) << 2;

  // bijective XCD swizzle (grid % 8 == 0 for all our launches)
  const int nwg = gridDim.x;
  const int orig = blockIdx.x;
  const int swz = (orig & 7) * (nwg >> 3) + (orig >> 3);
  const int mt = swz / NT, nt = swz - mt * NT;
  const int m0 = mt << 8, n0 = nt << 8;

  const size_t K2 = (size_t)K * 2;

  // staging: linear LDS dest (wave-uniform base + lane*16); pre-swizzled global src
  const int srow = tid >> 3;                  // row within 64-row chunk
  const int sg = tid & 7;                     // dest granule
  const int sgs = ((sg ^ (srow & 7)) << 4);   // swizzled source byte offset
  const char* pA = (const char*)A + (size_t)(m0 + srow) * K2 + sgs;
  const char* pB = (const char*)BT + (size_t)(n0 + srow) * K2 + sgs;
  char* sdA = (char*)&sA[0][0] + (wv << 10);
  char* sdB = (char*)&sB[0][0] + (wv << 10);

  // swizzled ds_read granule byte offsets per k-slice
  const int g0 = (((lane >> 4) ^ (fr & 7)) << 4);
  const int g1 = (((4 + (lane >> 4)) ^ (fr & 7)) << 4);
  const int arow = (wr << 7) + fr;
  const int brow = (wc << 6) + fr;

  f32x4 acc[8][4];
  #pragma unroll
  for (int i = 0; i < 8; ++i)
    #pragma unroll
    for (int j = 0; j < 4; ++j) acc[i][j] = (f32x4){0.f, 0.f, 0.f, 0.f};

  bf16x8 af[4][2];        // A frags, one M-half at a time
  bf16x8 bbv[2][2][2];    // B frags, both N-halves live
  const int KT = K >> 6;
  const int NI = KT >> 1;  // K-tiles processed 2 per iteration (KT even for all our shapes)

#define BARR __builtin_amdgcn_s_barrier()
#define SCB __builtin_amdgcn_sched_barrier(0)
#define LGKM0 asm volatile("s_waitcnt lgkmcnt(0)" ::: "memory")
#define VM2 asm volatile("s_waitcnt vmcnt(2)" ::: "memory")
#define VM0 asm volatile("s_waitcnt vmcnt(0)" ::: "memory")

#define LDA(CB, mh)                                                          \
  {                                                                          \
    const char* ba = ((const char*)&sA[0][0]) + (CB)*32768;                  \
    _Pragma("unroll") for (int fm = 0; fm < 4; ++fm) {                       \
      const int r = arow + (mh)*64 + fm * 16;                                \
      af[fm][0] = *(const bf16x8*)(ba + r * 128 + g0);                       \
      af[fm][1] = *(const bf16x8*)(ba + r * 128 + g1);                       \
    }                                                                        \
  }
#define LDB(CB, nh)                                                          \
  {                                                                          \
    const char* ba = ((const char*)&sB[0][0]) + (CB)*32768;                  \
    _Pragma("unroll") for (int fn = 0; fn < 2; ++fn) {                       \
      const int r = brow + (nh)*32 + fn * 16;                                \
      bbv[nh][fn][0] = *(const bf16x8*)(ba + r * 128 + g0);                  \
      bbv[nh][fn][1] = *(const bf16x8*)(ba + r * 128 + g1);                  \
    }                                                                        \
  }
#define STG(CB, tt, j)                                                       \
  {                                                                          \
    const size_t ko = (size_t)(tt) << 7;                                     \
    gld16(pA + (size_t)((j)*64) * K2 + ko, sdA + (CB)*32768 + (j)*8192);     \
    gld16(pB + (size_t)((j)*64) * K2 + ko, sdB + (CB)*32768 + (j)*8192);     \
  }
#define MMAQ(mh, nh)                                                         \
  _Pragma("unroll") for (int fm = 0; fm < 4; ++fm)                           \
      _Pragma("unroll") for (int fn = 0; fn < 2; ++fn) {                     \
    f32x4* ac = &acc[(mh)*4 + fm][(nh)*2 + fn];                              \
    *ac = __builtin_amdgcn_mfma_f32_16x16x32_bf16(af[fm][0], bbv[nh][fn][0], \
                                                  *ac, 0, 0, 0);             \
    *ac = __builtin_amdgcn_mfma_f32_16x16x32_bf16(af[fm][1], bbv[nh][fn][1], \
                                                  *ac, 0, 0, 0);             \
  }
#define OPEN  SCB; BARR; LGKM0; SCB; __builtin_amdgcn_s_setprio(1)
#define OPEN_NOLD  SCB; BARR; __builtin_amdgcn_s_setprio(1)
#define CLOSE __builtin_amdgcn_s_setprio(0)

  // prologue: tile0 fully (buf0) + tile1 chunk0 (buf1)
  #pragma unroll
  for (int j = 0; j < 4; ++j) STG(0, 0, j);
  STG(1, 1, 0);
  VM2;   // tile0's 8 loads landed; tile1 c0 may fly
  BARR;

  for (int i = 0; i < NI; ++i) {
    const int s1 = 2 * i + 1, s2 = 2 * i + 2, s3 = 2 * i + 3;
    const bool gl = (i + 1 < NI);  // stage tiles s2,s3 (KT even => same guard)
    // ---- K-tile 2i (buf0) ----
    // P0
    LDB(0, 0) LDA(0, 0) STG(1, s1, 1)
    OPEN; MMAQ(0, 0); CLOSE; BARR;
    // P1
    LDB(0, 1) STG(1, s1, 2)
    OPEN; MMAQ(0, 1); CLOSE; BARR;
    // P2
    LDA(0, 1) STG(1, s1, 3)
    OPEN; MMAQ(1, 1); CLOSE; BARR;
    // P3 (no ds_reads; bbv[0]/af still live)
    if (gl) STG(0, s2, 0)
    OPEN_NOLD; MMAQ(1, 0); CLOSE;
    if (gl) { VM2; } else { VM0; }   // tile s1 (buf1) landed for P4
    BARR;
    // ---- K-tile 2i+1 (buf1) ----
    // P4
    LDB(1, 0) LDA(1, 0)
    if (gl) STG(0, s2, 1)
    OPEN; MMAQ(0, 0); CLOSE; BARR;
    // P5
    LDB(1, 1)
    if (gl) STG(0, s2, 2)
    OPEN; MMAQ(0, 1); CLOSE; BARR;
    // P6
    LDA(1, 1)
    if (gl) STG(0, s2, 3)
    OPEN; MMAQ(1, 1); CLOSE; BARR;
    // P7
    if (gl) STG(1, s3, 0)
    OPEN_NOLD; MMAQ(1, 0); CLOSE;
    if (gl) { VM2; } else { VM0; }   // tile s2 (buf0) landed for next P0
    BARR;
  }
#undef BARR
#undef SCB
#undef LGKM0
#undef VM2
#undef VM0
#undef LDA
#undef LDB
#undef STG
#undef MMAQ
#undef OPEN
#undef OPEN_NOLD
#undef CLOSE

  #pragma unroll
  for (int ai = 0; ai < 8; ++ai) {
    #pragma unroll
    for (int bj = 0; bj < 4; ++bj) {
      const int col = n0 + (wc << 6) + bj * 16 + fr;
      const float bc = bias[col];
      #pragma unroll
      for (int i = 0; i < 4; ++i) {
        const int row = m0 + (wr << 7) + ai * 16 + q4 + i;
        float v = acc[ai][bj][i] + bc;
        if (EPI == 0) {
          outB[(size_t)row * N + col] = f2bf(v);
        } else if (EPI == 1) {
          int b = row >> 7, wid = (row >> 4) & 7, tok = row & 15;
          int oh = (((wid >> 2) << 2) + (tok >> 2) + 2) & 7;
          int ow = (((wid & 3) << 2) + (tok & 3) + 2) & 15;
          size_t di = ((size_t)(b << 7) + oh * 16 + ow) * 768 + col;
          outF[di] = v + resid[di];
        } else if (EPI == 2) {
          float g = 0.5f * v * (1.0f + erff(v * 0.70710678118f));
          outB[(size_t)row * N + col] = f2bf(g);
        } else {
          size_t di = (size_t)row * N + col;
          outF[di] = v + resid[di];
        }
      }
    }
  }
}

// ---------- window attention: one wave per (window, head) ----------
__global__ __launch_bounds__(64) void attn_win(const unsigned short* __restrict__ qkv,
                                               const float* __restrict__ rel_table,
                                               unsigned short* __restrict__ o) {
  __shared__ __align__(16) unsigned short q_s[16 * 64];
  __shared__ __align__(16) unsigned short k_s[16 * 64];
  __shared__ __align__(16) unsigned short vt_s[64 * 32];  // [d][m], m padded to 32
  __shared__ __align__(16) unsigned short p_s[16 * 32];   // [n][m], m padded to 32
  const int bid = blockIdx.x;
  const int win = bid / 12;
  const int head = bid - win * 12;
  const int wid = win & 7;
  const int lane = threadIdx.x;
  const unsigned short* gq =
      qkv + (size_t)win * 16 * 2304 + head * 64 + (size_t)(lane >> 2) * 2304 + ((lane & 3) << 4);
  const int t = lane >> 2, d0 = (lane & 3) << 4;
  *(uint4v*)&q_s[t * 64 + d0]     = *(const uint4v*)(gq);
  *(uint4v*)&q_s[t * 64 + d0 + 8] = *(const uint4v*)(gq + 8);
  *(uint4v*)&k_s[t * 64 + d0]     = *(const uint4v*)(gq + 768);
  *(uint4v*)&k_s[t * 64 + d0 + 8] = *(const uint4v*)(gq + 776);
  unsigned short vv[16];
  *(uint4v*)&vv[0] = *(const uint4v*)(gq + 1536);
  *(uint4v*)&vv[8] = *(const uint4v*)(gq + 1544);
  #pragma unroll
  for (int e = 0; e < 16; ++e) vt_s[(d0 + e) * 32 + t] = vv[e];
  #pragma unroll
  for (int e = 0; e < 16; ++e) vt_s[lane * 32 + 16 + e] = 0;  // K-pad of V
  if (lane < 16) {
    #pragma unroll
    for (int e = 0; e < 16; ++e) p_s[lane * 32 + 16 + e] = 0;  // K-pad of P
  }
  __syncthreads();

  const int fr = lane & 15, kg = (lane >> 4) << 3;
  bf16x8 qa0 = *(const bf16x8*)&q_s[fr * 64 + kg];
  bf16x8 qa1 = *(const bf16x8*)&q_s[fr * 64 + 32 + kg];
  bf16x8 ka0 = *(const bf16x8*)&k_s[fr * 64 + kg];
  bf16x8 ka1 = *(const bf16x8*)&k_s[fr * 64 + 32 + kg];
  f32x4 s = (f32x4){0.f, 0.f, 0.f, 0.f};
  s = __builtin_amdgcn_mfma_f32_16x16x32_bf16(qa0, ka0, s, 0, 0, 0);
  s = __builtin_amdgcn_mfma_f32_16x16x32_bf16(qa1, ka1, s, 0, 0, 0);
  // S[n][m]: n = (lane>>4)*4 + i, m = fr

  const int wh = wid >> 2, wwc = wid & 3;
  const int rj = fr >> 2, cj = fr & 3;
  const int rowm = wh * 4 + rj, colm = wwc * 4 + cj;
  const int rgm = (rowm < 4 ? 0 : (rowm < 6 ? 1 : 2)) * 3 +
                  (colm < 12 ? 0 : (colm < 14 ? 1 : 2));
  float p[4];
  #pragma unroll
  for (int i = 0; i < 4; ++i) {
    int n = ((lane >> 4) << 2) + i;
    int ri = n >> 2, ci = n & 3;
    int rown = wh * 4 + ri, coln = wwc * 4 + ci;
    int rgn = (rown < 4 ? 0 : (rown < 6 ? 1 : 2)) * 3 +
              (coln < 12 ? 0 : (coln < 14 ? 1 : 2));
    float bias = rel_table[(size_t)((ri - rj + 3) * 7 + (ci - cj + 3)) * 12 + head];
    p[i] = s[i] * 0.125f + bias + (rgn != rgm ? -100.0f : 0.0f);
  }
  float mx[4] = {p[0], p[1], p[2], p[3]};
  #pragma unroll
  for (int off = 8; off > 0; off >>= 1)
    #pragma unroll
    for (int i = 0; i < 4; ++i) mx[i] = fmaxf(mx[i], __shfl_xor(mx[i], off, 64));
  float sm[4];
  #pragma unroll
  for (int i = 0; i < 4; ++i) { p[i] = __expf(p[i] - mx[i]); sm[i] = p[i]; }
  #pragma unroll
  for (int off = 8; off > 0; off >>= 1)
    #pragma unroll
    for (int i = 0; i < 4; ++i) sm[i] += __shfl_xor(sm[i], off, 64);
  #pragma unroll
  for (int i = 0; i < 4; ++i)
    p_s[(((lane >> 4) << 2) + i) * 32 + fr] = f2bf(p[i] / sm[i]);
  __syncthreads();

  bf16x8 pa = *(const bf16x8*)&p_s[fr * 32 + kg];
  const f32x4 oz = (f32x4){0.f, 0.f, 0.f, 0.f};
  #pragma unroll
  for (int c = 0; c < 4; ++c) {
    bf16x8 vb = *(const bf16x8*)&vt_s[(c * 16 + fr) * 32 + kg];
    f32x4 oa = __builtin_amdgcn_mfma_f32_16x16x32_bf16(pa, vb, oz, 0, 0, 0);
    #pragma unroll
    for (int i = 0; i < 4; ++i) {
      int n = ((lane >> 4) << 2) + i;
      o[((size_t)win * 16 + n) * 768 + head * 64 + c * 16 + fr] = f2bf(oa[i]);
    }
  }
}

extern "C" void kernel_launch(void* const* d_in, const int* in_sizes, int n_in,
                              void* d_out, int out_size, void* d_ws, size_t ws_size,
                              hipStream_t stream) {
  const float* x      = (const float*)d_in[0];
  const float* ln1_g  = (const float*)d_in[1];
  const float* ln1_b  = (const float*)d_in[2];
  const float* qkv_w  = (const float*)d_in[3];
  const float* qkv_b  = (const float*)d_in[4];
  const float* proj_w = (const float*)d_in[5];
  const float* proj_b = (const float*)d_in[6];
  const float* rel_t  = (const float*)d_in[7];
  const float* ln2_g  = (const float*)d_in[8];
  const float* ln2_b  = (const float*)d_in[9];
  const float* fc1_w  = (const float*)d_in[10];
  const float* fc1_b  = (const float*)d_in[11];
  const float* fc2_w  = (const float*)d_in[12];
  const float* fc2_b  = (const float*)d_in[13];
  float* out = (float*)d_out;

  char* ws = (char*)d_ws;
  // region A (50,331,648 B): hw -> o -> y  (all [32768][768] bf16, sequential reuse)
  unsigned short* wsA = (unsigned short*)(ws);
  // region B: qkv bf16 [32768][2304]; later xr fp32 [32768][768]
  unsigned short* qkvb = (unsigned short*)(ws + 50331648);
  float* xr = (float*)(ws + 50331648);
  // region C: h1 bf16 [32768][1024]
  unsigned short* h1 = (unsigned short*)(ws + 201326592);
  // bf16 transposed weights
  unsigned short* qkv_wT = (unsigned short*)(ws + 268435456);  // [2304][768]
  unsigned short* proj_wT = (unsigned short*)(ws + 271974400); // [768][768]
  unsigned short* fc1_wT = (unsigned short*)(ws + 273154048);  // [1024][768]
  unsigned short* fc2_wT = (unsigned short*)(ws + 274726912);  // [768][1024]

  dim3 tb(32, 8);
  transpose_cast<<<dim3(2304 / 32, 768 / 32), tb, 0, stream>>>(qkv_w, qkv_wT, 768, 2304);
  transpose_cast<<<dim3(768 / 32, 768 / 32), tb, 0, stream>>>(proj_w, proj_wT, 768, 768);
  transpose_cast<<<dim3(1024 / 32, 768 / 32), tb, 0, stream>>>(fc1_w, fc1_wT, 768, 1024);
  transpose_cast<<<dim3(768 / 32, 1024 / 32), tb, 0, stream>>>(fc2_w, fc2_wT, 1024, 768);

  ln_kernel<0><<<32768, 256, 0, stream>>>(x, ln1_g, ln1_b, wsA);                 // hw
  gemm256<0><<<dim3(128 * 9), 512, 0, stream>>>(wsA, qkv_wT, qkv_b, nullptr, qkvb,
                                                nullptr, 32768, 2304, 768, 9);   // qkv
  attn_win<<<24576, 64, 0, stream>>>(qkvb, rel_t, wsA);                          // o
  gemm256<1><<<dim3(128 * 3), 512, 0, stream>>>(wsA, proj_wT, proj_b, xr, nullptr,
                                                x, 32768, 768, 768, 3);          // xr = x + proj(o)
  ln_kernel<1><<<32768, 256, 0, stream>>>(xr, ln2_g, ln2_b, wsA);                // y
  gemm256<2><<<dim3(128 * 4), 512, 0, stream>>>(wsA, fc1_wT, fc1_b, nullptr, h1,
                                                nullptr, 32768, 1024, 768, 4);   // h1 = gelu(...)
  gemm256<3><<<dim3(128 * 3), 512, 0, stream>>>(h1, fc2_wT, fc2_b, out, nullptr,
                                                xr, 32768, 768, 1024, 3);        // out = xr + fc2(h1)
}

// Round 5
// 545.581 us; speedup vs baseline: 1.1306x; 1.0638x over previous
//
#include <hip/hip_runtime.h>
#include <stdint.h>
#include <stddef.h>

typedef __attribute__((ext_vector_type(8))) short bf16x8;
typedef __attribute__((ext_vector_type(4))) float f32x4;
typedef __attribute__((ext_vector_type(4))) unsigned int uint4v;

static __device__ __forceinline__ unsigned short f2bf(float f) {
  unsigned int u = __builtin_bit_cast(unsigned int, f);
  unsigned int r = (u + 0x7FFFu + ((u >> 16) & 1u)) >> 16;
  return (unsigned short)r;
}

static __device__ __forceinline__ void gld16(const void* g, void* l) {
  __builtin_amdgcn_global_load_lds(
      (const __attribute__((address_space(1))) void*)g,
      (__attribute__((address_space(3))) void*)l, 16, 0, 0);
}

// ---------- weight transpose + cast: src [R][C] f32 -> dst [C][R] bf16 ----------
__global__ void transpose_cast(const float* __restrict__ src,
                               unsigned short* __restrict__ dst, int R, int C) {
  __shared__ float tile[32][33];
  int c0 = blockIdx.x * 32, r0 = blockIdx.y * 32;
  int tx = threadIdx.x, ty = threadIdx.y;  // (32, 8)
  #pragma unroll
  for (int i = 0; i < 32; i += 8)
    tile[ty + i][tx] = src[(size_t)(r0 + ty + i) * C + c0 + tx];
  __syncthreads();
  #pragma unroll
  for (int i = 0; i < 32; i += 8)
    dst[(size_t)(c0 + ty + i) * R + r0 + tx] = f2bf(tile[tx][ty + i]);
}

// ---------- block reduce ----------
static __device__ __forceinline__ float blksum256(float v, float* sb) {
  #pragma unroll
  for (int o = 32; o > 0; o >>= 1) v += __shfl_down(v, o, 64);
  int lane = threadIdx.x & 63, w = threadIdx.x >> 6;
  __syncthreads();
  if (lane == 0) sb[w] = v;
  __syncthreads();
  return sb[0] + sb[1] + sb[2] + sb[3];
}

// ---------- LayerNorm (MODE 0: write shifted/window-partitioned rows; MODE 1: identity) ----------
template <int MODE>
__global__ __launch_bounds__(256) void ln_kernel(const float* __restrict__ x,
                                                 const float* __restrict__ gg,
                                                 const float* __restrict__ bb,
                                                 unsigned short* __restrict__ out) {
  __shared__ float sb[4];
  const int d = blockIdx.x;  // dest row (window order for MODE 0)
  size_t srow;
  if (MODE == 0) {
    int b = d >> 7, wid = (d >> 4) & 7, tok = d & 15;
    int oh = (((wid >> 2) << 2) + (tok >> 2) + 2) & 7;
    int ow = (((wid & 3) << 2) + (tok & 3) + 2) & 15;
    srow = (size_t)(b << 7) + oh * 16 + ow;
  } else {
    srow = d;
  }
  const float* xr = x + srow * 768;
  const int t = threadIdx.x;
  float v0 = xr[t], v1 = xr[t + 256], v2 = xr[t + 512];
  float mean = blksum256(v0 + v1 + v2, sb) * (1.0f / 768.0f);
  float d0 = v0 - mean, d1 = v1 - mean, d2 = v2 - mean;
  float var = blksum256(d0 * d0 + d1 * d1 + d2 * d2, sb) * (1.0f / 768.0f);
  float rstd = rsqrtf(var + 1e-5f);
  size_t o = (size_t)d * 768;
  out[o + t]       = f2bf(d0 * rstd * gg[t] + bb[t]);
  out[o + t + 256] = f2bf(d1 * rstd * gg[t + 256] + bb[t + 256]);
  out[o + t + 512] = f2bf(d2 * rstd * gg[t + 512] + bb[t + 512]);
}

// ---------- 256x256 8-wave 8-phase GEMM (deep-cover staging, race-fixed): C = A @ BT^T + bias ----------
// Chunk liveness per K-tile (reads P0: LDB(n0)+LDA(m0), P1: LDB(n1), P2: LDA(m1)):
//   A chunks {0,2} dead after P0; B chunks {0..3} dead after P1; A chunks {1,3} dead after P2.
// Stage slots: P1 -> A0,A2 ; P2 -> B0,B1 ; P3 -> A1,A3,B2,B3 (mirror P5/P6/P7 for odd tile).
// vmcnt(8) at P3/P7 drains exactly the 8 oldest loads (= the buffer consumed next);
// every load gets 4-6 phases of cover before its wait.
// EPI 0: +bias -> bf16 (qkv)
// EPI 1: +bias, window-reverse+unshift scatter, +resid(x) -> fp32 xr (proj)
// EPI 2: +bias, exact gelu -> bf16 (fc1)
// EPI 3: +bias, +resid(xr) -> fp32 out (fc2)
template <int EPI>
__global__ __launch_bounds__(512, 2) void gemm256(
    const unsigned short* __restrict__ A, const unsigned short* __restrict__ BT,
    const float* __restrict__ bias, float* __restrict__ outF,
    unsigned short* __restrict__ outB, const float* __restrict__ resid,
    int M, int N, int K, int NT) {
  // per K-tile buffer: 256 rows x 64 K bf16, row stride 128B, 16B-granule swizzled by row&7
  // even K-tiles -> buf 0, odd -> buf 1 (static parity, no runtime indexing)
  __shared__ __align__(16) unsigned short sA[2][256 * 64];
  __shared__ __align__(16) unsigned short sB[2][256 * 64];

  const int tid = threadIdx.x;
  const int lane = tid & 63, wv = tid >> 6;
  const int wr = wv >> 2, wc = wv & 3;        // 2 (M) x 4 (N) wave grid
  const int fr = lane & 15, q4 = (lane >> 4) << 2;

  // bijective XCD swizzle (grid % 8 == 0 for all our launches)
  const int nwg = gridDim.x;
  const int orig = blockIdx.x;
  const int swz = (orig & 7) * (nwg >> 3) + (orig >> 3);
  const int mt = swz / NT, nt = swz - mt * NT;
  const int m0 = mt << 8, n0 = nt << 8;

  const size_t K2 = (size_t)K * 2;

  // staging: linear LDS dest (wave-uniform base + lane*16); pre-swizzled global src
  const int srow = tid >> 3;                  // row within 64-row chunk
  const int sg = tid & 7;                     // dest granule
  const int sgs = ((sg ^ (srow & 7)) << 4);   // swizzled source byte offset
  const char* pA = (const char*)A + (size_t)(m0 + srow) * K2 + sgs;
  const char* pB = (const char*)BT + (size_t)(n0 + srow) * K2 + sgs;
  char* sdA = (char*)&sA[0][0] + (wv << 10);
  char* sdB = (char*)&sB[0][0] + (wv << 10);

  // swizzled ds_read granule byte offsets per k-slice
  const int g0 = (((lane >> 4) ^ (fr & 7)) << 4);
  const int g1 = (((4 + (lane >> 4)) ^ (fr & 7)) << 4);
  const int arow = (wr << 7) + fr;
  const int brow = (wc << 6) + fr;

  f32x4 acc[8][4];
  #pragma unroll
  for (int i = 0; i < 8; ++i)
    #pragma unroll
    for (int j = 0; j < 4; ++j) acc[i][j] = (f32x4){0.f, 0.f, 0.f, 0.f};

  bf16x8 af[4][2];        // A frags, one M-half at a time
  bf16x8 bbv[2][2][2];    // B frags, both N-halves live
  const int KT = K >> 6;
  const int NI = KT >> 1;  // 2 K-tiles per iteration (KT even, >=4 for all our shapes)

#define BARR __builtin_amdgcn_s_barrier()
#define SCB __builtin_amdgcn_sched_barrier(0)
#define LGKM0 asm volatile("s_waitcnt lgkmcnt(0)" ::: "memory")
#define VM8 asm volatile("s_waitcnt vmcnt(8)" ::: "memory")
#define VM0 asm volatile("s_waitcnt vmcnt(0)" ::: "memory")

#define LDA(CB, mh)                                                          \
  {                                                                          \
    const char* ba = ((const char*)&sA[0][0]) + (CB)*32768;                  \
    _Pragma("unroll") for (int fm = 0; fm < 4; ++fm) {                       \
      const int r = arow + (mh)*64 + fm * 16;                                \
      af[fm][0] = *(const bf16x8*)(ba + r * 128 + g0);                       \
      af[fm][1] = *(const bf16x8*)(ba + r * 128 + g1);                       \
    }                                                                        \
  }
#define LDB(CB, nh)                                                          \
  {                                                                          \
    const char* ba = ((const char*)&sB[0][0]) + (CB)*32768;                  \
    _Pragma("unroll") for (int fn = 0; fn < 2; ++fn) {                       \
      const int r = brow + (nh)*32 + fn * 16;                                \
      bbv[nh][fn][0] = *(const bf16x8*)(ba + r * 128 + g0);                  \
      bbv[nh][fn][1] = *(const bf16x8*)(ba + r * 128 + g1);                  \
    }                                                                        \
  }
#define STGA(CB, tt, j)                                                      \
  gld16(pA + (size_t)((j)*64) * K2 + ((size_t)(tt) << 7),                    \
        sdA + (CB)*32768 + (j)*8192);
#define STGB(CB, tt, j)                                                      \
  gld16(pB + (size_t)((j)*64) * K2 + ((size_t)(tt) << 7),                    \
        sdB + (CB)*32768 + (j)*8192);
#define MMAQ(mh, nh)                                                         \
  _Pragma("unroll") for (int fm = 0; fm < 4; ++fm)                           \
      _Pragma("unroll") for (int fn = 0; fn < 2; ++fn) {                     \
    f32x4* ac = &acc[(mh)*4 + fm][(nh)*2 + fn];                              \
    *ac = __builtin_amdgcn_mfma_f32_16x16x32_bf16(af[fm][0], bbv[nh][fn][0], \
                                                  *ac, 0, 0, 0);             \
    *ac = __builtin_amdgcn_mfma_f32_16x16x32_bf16(af[fm][1], bbv[nh][fn][1], \
                                                  *ac, 0, 0, 0);             \
  }
#define OPEN  SCB; BARR; LGKM0; SCB; __builtin_amdgcn_s_setprio(1)
#define OPEN_NOLD  SCB; BARR; __builtin_amdgcn_s_setprio(1)
#define CLOSE __builtin_amdgcn_s_setprio(0)

  // prologue: stage tile0 (buf0) fully, then tile1 (buf1) fully; wait buf0 only
  #pragma unroll
  for (int j = 0; j < 4; ++j) { STGA(0, 0, j); STGB(0, 0, j); }
  #pragma unroll
  for (int j = 0; j < 4; ++j) { STGA(1, 1, j); STGB(1, 1, j); }
  VM8;   // buf0's 8 loads landed; buf1's 8 still in flight
  BARR;

  for (int i = 0; i < NI; ++i) {
    const int s2 = 2 * i + 2, s3 = 2 * i + 3;
    const bool gl = (i + 1 < NI);
    // ---- K-tile 2i (buf0) ----
    // P0 (12 ds_reads; no staging)
    LDB(0, 0) LDA(0, 0)
    OPEN; MMAQ(0, 0); CLOSE; BARR;
    // P1: A chunks 0,2 of buf0 dead (fully read at P0) -> stage next tile's A0,A2
    LDB(0, 1)
    if (gl) { STGA(0, s2, 0); STGA(0, s2, 2); }
    OPEN; MMAQ(0, 1); CLOSE; BARR;
    // P2: all B chunks of buf0 dead (read at P0+P1) -> stage B0,B1
    LDA(0, 1)
    if (gl) { STGB(0, s2, 0); STGB(0, s2, 1); }
    OPEN; MMAQ(1, 1); CLOSE; BARR;
    // P3: A chunks 1,3 dead (read at P2) -> stage A1,A3 + B2,B3
    if (gl) { STGA(0, s2, 1); STGA(0, s2, 3); STGB(0, s2, 2); STGB(0, s2, 3); }
    OPEN_NOLD; MMAQ(1, 0); CLOSE;
    if (gl) { VM8; } else { VM0; }   // drain 8 oldest (= buf1's tile); keep buf0-next in flight
    BARR;
    // ---- K-tile 2i+1 (buf1) ----
    // P4
    LDB(1, 0) LDA(1, 0)
    OPEN; MMAQ(0, 0); CLOSE; BARR;
    // P5: buf1 A chunks 0,2 dead -> stage A0,A2
    LDB(1, 1)
    if (gl) { STGA(1, s3, 0); STGA(1, s3, 2); }
    OPEN; MMAQ(0, 1); CLOSE; BARR;
    // P6: buf1 B chunks dead -> stage B0,B1
    LDA(1, 1)
    if (gl) { STGB(1, s3, 0); STGB(1, s3, 1); }
    OPEN; MMAQ(1, 1); CLOSE; BARR;
    // P7: buf1 A chunks 1,3 dead -> stage A1,A3 + B2,B3
    if (gl) { STGA(1, s3, 1); STGA(1, s3, 3); STGB(1, s3, 2); STGB(1, s3, 3); }
    OPEN_NOLD; MMAQ(1, 0); CLOSE;
    if (gl) { VM8; }                 // drain 8 oldest (= buf0-next's tile)
    BARR;
  }
#undef BARR
#undef SCB
#undef LGKM0
#undef VM8
#undef VM0
#undef LDA
#undef LDB
#undef STGA
#undef STGB
#undef MMAQ
#undef OPEN
#undef OPEN_NOLD
#undef CLOSE

  #pragma unroll
  for (int ai = 0; ai < 8; ++ai) {
    #pragma unroll
    for (int bj = 0; bj < 4; ++bj) {
      const int col = n0 + (wc << 6) + bj * 16 + fr;
      const float bc = bias[col];
      #pragma unroll
      for (int i = 0; i < 4; ++i) {
        const int row = m0 + (wr << 7) + ai * 16 + q4 + i;
        float v = acc[ai][bj][i] + bc;
        if (EPI == 0) {
          outB[(size_t)row * N + col] = f2bf(v);
        } else if (EPI == 1) {
          int b = row >> 7, wid = (row >> 4) & 7, tok = row & 15;
          int oh = (((wid >> 2) << 2) + (tok >> 2) + 2) & 7;
          int ow = (((wid & 3) << 2) + (tok & 3) + 2) & 15;
          size_t di = ((size_t)(b << 7) + oh * 16 + ow) * 768 + col;
          outF[di] = v + resid[di];
        } else if (EPI == 2) {
          float g = 0.5f * v * (1.0f + erff(v * 0.70710678118f));
          outB[(size_t)row * N + col] = f2bf(g);
        } else {
          size_t di = (size_t)row * N + col;
          outF[di] = v + resid[di];
        }
      }
    }
  }
}

// ---------- window attention: one wave per (window, head) ----------
__global__ __launch_bounds__(64) void attn_win(const unsigned short* __restrict__ qkv,
                                               const float* __restrict__ rel_table,
                                               unsigned short* __restrict__ o) {
  __shared__ __align__(16) unsigned short q_s[16 * 64];
  __shared__ __align__(16) unsigned short k_s[16 * 64];
  __shared__ __align__(16) unsigned short vt_s[64 * 32];  // [d][m], m padded to 32
  __shared__ __align__(16) unsigned short p_s[16 * 32];   // [n][m], m padded to 32
  const int bid = blockIdx.x;
  const int win = bid / 12;
  const int head = bid - win * 12;
  const int wid = win & 7;
  const int lane = threadIdx.x;
  const unsigned short* gq =
      qkv + (size_t)win * 16 * 2304 + head * 64 + (size_t)(lane >> 2) * 2304 + ((lane & 3) << 4);
  const int t = lane >> 2, d0 = (lane & 3) << 4;
  *(uint4v*)&q_s[t * 64 + d0]     = *(const uint4v*)(gq);
  *(uint4v*)&q_s[t * 64 + d0 + 8] = *(const uint4v*)(gq + 8);
  *(uint4v*)&k_s[t * 64 + d0]     = *(const uint4v*)(gq + 768);
  *(uint4v*)&k_s[t * 64 + d0 + 8] = *(const uint4v*)(gq + 776);
  unsigned short vv[16];
  *(uint4v*)&vv[0] = *(const uint4v*)(gq + 1536);
  *(uint4v*)&vv[8] = *(const uint4v*)(gq + 1544);
  #pragma unroll
  for (int e = 0; e < 16; ++e) vt_s[(d0 + e) * 32 + t] = vv[e];
  #pragma unroll
  for (int e = 0; e < 16; ++e) vt_s[lane * 32 + 16 + e] = 0;  // K-pad of V
  if (lane < 16) {
    #pragma unroll
    for (int e = 0; e < 16; ++e) p_s[lane * 32 + 16 + e] = 0;  // K-pad of P
  }
  __syncthreads();

  const int fr = lane & 15, kg = (lane >> 4) << 3;
  bf16x8 qa0 = *(const bf16x8*)&q_s[fr * 64 + kg];
  bf16x8 qa1 = *(const bf16x8*)&q_s[fr * 64 + 32 + kg];
  bf16x8 ka0 = *(const bf16x8*)&k_s[fr * 64 + kg];
  bf16x8 ka1 = *(const bf16x8*)&k_s[fr * 64 + 32 + kg];
  f32x4 s = (f32x4){0.f, 0.f, 0.f, 0.f};
  s = __builtin_amdgcn_mfma_f32_16x16x32_bf16(qa0, ka0, s, 0, 0, 0);
  s = __builtin_amdgcn_mfma_f32_16x16x32_bf16(qa1, ka1, s, 0, 0, 0);
  // S[n][m]: n = (lane>>4)*4 + i, m = fr

  const int wh = wid >> 2, wwc = wid & 3;
  const int rj = fr >> 2, cj = fr & 3;
  const int rowm = wh * 4 + rj, colm = wwc * 4 + cj;
  const int rgm = (rowm < 4 ? 0 : (rowm < 6 ? 1 : 2)) * 3 +
                  (colm < 12 ? 0 : (colm < 14 ? 1 : 2));
  float p[4];
  #pragma unroll
  for (int i = 0; i < 4; ++i) {
    int n = ((lane >> 4) << 2) + i;
    int ri = n >> 2, ci = n & 3;
    int rown = wh * 4 + ri, coln = wwc * 4 + ci;
    int rgn = (rown < 4 ? 0 : (rown < 6 ? 1 : 2)) * 3 +
              (coln < 12 ? 0 : (coln < 14 ? 1 : 2));
    float bias = rel_table[(size_t)((ri - rj + 3) * 7 + (ci - cj + 3)) * 12 + head];
    p[i] = s[i] * 0.125f + bias + (rgn != rgm ? -100.0f : 0.0f);
  }
  float mx[4] = {p[0], p[1], p[2], p[3]};
  #pragma unroll
  for (int off = 8; off > 0; off >>= 1)
    #pragma unroll
    for (int i = 0; i < 4; ++i) mx[i] = fmaxf(mx[i], __shfl_xor(mx[i], off, 64));
  float sm[4];
  #pragma unroll
  for (int i = 0; i < 4; ++i) { p[i] = __expf(p[i] - mx[i]); sm[i] = p[i]; }
  #pragma unroll
  for (int off = 8; off > 0; off >>= 1)
    #pragma unroll
    for (int i = 0; i < 4; ++i) sm[i] += __shfl_xor(sm[i], off, 64);
  #pragma unroll
  for (int i = 0; i < 4; ++i)
    p_s[(((lane >> 4) << 2) + i) * 32 + fr] = f2bf(p[i] / sm[i]);
  __syncthreads();

  bf16x8 pa = *(const bf16x8*)&p_s[fr * 32 + kg];
  const f32x4 oz = (f32x4){0.f, 0.f, 0.f, 0.f};
  #pragma unroll
  for (int c = 0; c < 4; ++c) {
    bf16x8 vb = *(const bf16x8*)&vt_s[(c * 16 + fr) * 32 + kg];
    f32x4 oa = __builtin_amdgcn_mfma_f32_16x16x32_bf16(pa, vb, oz, 0, 0, 0);
    #pragma unroll
    for (int i = 0; i < 4; ++i) {
      int n = ((lane >> 4) << 2) + i;
      o[((size_t)win * 16 + n) * 768 + head * 64 + c * 16 + fr] = f2bf(oa[i]);
    }
  }
}

extern "C" void kernel_launch(void* const* d_in, const int* in_sizes, int n_in,
                              void* d_out, int out_size, void* d_ws, size_t ws_size,
                              hipStream_t stream) {
  const float* x      = (const float*)d_in[0];
  const float* ln1_g  = (const float*)d_in[1];
  const float* ln1_b  = (const float*)d_in[2];
  const float* qkv_w  = (const float*)d_in[3];
  const float* qkv_b  = (const float*)d_in[4];
  const float* proj_w = (const float*)d_in[5];
  const float* proj_b = (const float*)d_in[6];
  const float* rel_t  = (const float*)d_in[7];
  const float* ln2_g  = (const float*)d_in[8];
  const float* ln2_b  = (const float*)d_in[9];
  const float* fc1_w  = (const float*)d_in[10];
  const float* fc1_b  = (const float*)d_in[11];
  const float* fc2_w  = (const float*)d_in[12];
  const float* fc2_b  = (const float*)d_in[13];
  float* out = (float*)d_out;

  char* ws = (char*)d_ws;
  // region A (50,331,648 B): hw -> o -> y  (all [32768][768] bf16, sequential reuse)
  unsigned short* wsA = (unsigned short*)(ws);
  // region B: qkv bf16 [32768][2304]; later xr fp32 [32768][768]
  unsigned short* qkvb = (unsigned short*)(ws + 50331648);
  float* xr = (float*)(ws + 50331648);
  // region C: h1 bf16 [32768][1024]
  unsigned short* h1 = (unsigned short*)(ws + 201326592);
  // bf16 transposed weights
  unsigned short* qkv_wT = (unsigned short*)(ws + 268435456);  // [2304][768]
  unsigned short* proj_wT = (unsigned short*)(ws + 271974400); // [768][768]
  unsigned short* fc1_wT = (unsigned short*)(ws + 273154048);  // [1024][768]
  unsigned short* fc2_wT = (unsigned short*)(ws + 274726912);  // [768][1024]

  dim3 tb(32, 8);
  transpose_cast<<<dim3(2304 / 32, 768 / 32), tb, 0, stream>>>(qkv_w, qkv_wT, 768, 2304);
  transpose_cast<<<dim3(768 / 32, 768 / 32), tb, 0, stream>>>(proj_w, proj_wT, 768, 768);
  transpose_cast<<<dim3(1024 / 32, 768 / 32), tb, 0, stream>>>(fc1_w, fc1_wT, 768, 1024);
  transpose_cast<<<dim3(768 / 32, 1024 / 32), tb, 0, stream>>>(fc2_w, fc2_wT, 1024, 768);

  ln_kernel<0><<<32768, 256, 0, stream>>>(x, ln1_g, ln1_b, wsA);                 // hw
  gemm256<0><<<dim3(128 * 9), 512, 0, stream>>>(wsA, qkv_wT, qkv_b, nullptr, qkvb,
                                                nullptr, 32768, 2304, 768, 9);   // qkv
  attn_win<<<24576, 64, 0, stream>>>(qkvb, rel_t, wsA);                          // o
  gemm256<1><<<dim3(128 * 3), 512, 0, stream>>>(wsA, proj_wT, proj_b, xr, nullptr,
                                                x, 32768, 768, 768, 3);          // xr = x + proj(o)
  ln_kernel<1><<<32768, 256, 0, stream>>>(xr, ln2_g, ln2_b, wsA);                // y
  gemm256<2><<<dim3(128 * 4), 512, 0, stream>>>(wsA, fc1_wT, fc1_b, nullptr, h1,
                                                nullptr, 32768, 1024, 768, 4);   // h1 = gelu(...)
  gemm256<3><<<dim3(128 * 3), 512, 0, stream>>>(h1, fc2_wT, fc2_b, out, nullptr,
                                                xr, 32768, 768, 1024, 3);        // out = xr + fc2(h1)
}

// Round 6
// 543.605 us; speedup vs baseline: 1.1347x; 1.0036x over previous
//
#include <hip/hip_runtime.h>
#include <stdint.h>
#include <stddef.h>

typedef __attribute__((ext_vector_type(8))) short bf16x8;
typedef __attribute__((ext_vector_type(4))) float f32x4;
typedef __attribute__((ext_vector_type(4))) unsigned int uint4v;

static __device__ __forceinline__ unsigned short f2bf(float f) {
  unsigned int u = __builtin_bit_cast(unsigned int, f);
  unsigned int r = (u + 0x7FFFu + ((u >> 16) & 1u)) >> 16;
  return (unsigned short)r;
}

static __device__ __forceinline__ void gld16(const void* g, void* l) {
  __builtin_amdgcn_global_load_lds(
      (const __attribute__((address_space(1))) void*)g,
      (__attribute__((address_space(3))) void*)l, 16, 0, 0);
}

// ---------- weight transpose + cast: src [R][C] f32 -> dst [C][R] bf16 ----------
__global__ void transpose_cast(const float* __restrict__ src,
                               unsigned short* __restrict__ dst, int R, int C) {
  __shared__ float tile[32][33];
  int c0 = blockIdx.x * 32, r0 = blockIdx.y * 32;
  int tx = threadIdx.x, ty = threadIdx.y;  // (32, 8)
  #pragma unroll
  for (int i = 0; i < 32; i += 8)
    tile[ty + i][tx] = src[(size_t)(r0 + ty + i) * C + c0 + tx];
  __syncthreads();
  #pragma unroll
  for (int i = 0; i < 32; i += 8)
    dst[(size_t)(c0 + ty + i) * R + r0 + tx] = f2bf(tile[tx][ty + i]);
}

// ---------- block reduce ----------
static __device__ __forceinline__ float blksum256(float v, float* sb) {
  #pragma unroll
  for (int o = 32; o > 0; o >>= 1) v += __shfl_down(v, o, 64);
  int lane = threadIdx.x & 63, w = threadIdx.x >> 6;
  __syncthreads();
  if (lane == 0) sb[w] = v;
  __syncthreads();
  return sb[0] + sb[1] + sb[2] + sb[3];
}

// ---------- LayerNorm (MODE 0: write shifted/window-partitioned rows; MODE 1: identity) ----------
template <int MODE>
__global__ __launch_bounds__(256) void ln_kernel(const float* __restrict__ x,
                                                 const float* __restrict__ gg,
                                                 const float* __restrict__ bb,
                                                 unsigned short* __restrict__ out) {
  __shared__ float sb[4];
  const int d = blockIdx.x;  // dest row (window order for MODE 0)
  size_t srow;
  if (MODE == 0) {
    int b = d >> 7, wid = (d >> 4) & 7, tok = d & 15;
    int oh = (((wid >> 2) << 2) + (tok >> 2) + 2) & 7;
    int ow = (((wid & 3) << 2) + (tok & 3) + 2) & 15;
    srow = (size_t)(b << 7) + oh * 16 + ow;
  } else {
    srow = d;
  }
  const float* xr = x + srow * 768;
  const int t = threadIdx.x;
  float v0 = xr[t], v1 = xr[t + 256], v2 = xr[t + 512];
  float mean = blksum256(v0 + v1 + v2, sb) * (1.0f / 768.0f);
  float d0 = v0 - mean, d1 = v1 - mean, d2 = v2 - mean;
  float var = blksum256(d0 * d0 + d1 * d1 + d2 * d2, sb) * (1.0f / 768.0f);
  float rstd = rsqrtf(var + 1e-5f);
  size_t o = (size_t)d * 768;
  out[o + t]       = f2bf(d0 * rstd * gg[t] + bb[t]);
  out[o + t + 256] = f2bf(d1 * rstd * gg[t + 256] + bb[t + 256]);
  out[o + t + 512] = f2bf(d2 * rstd * gg[t + 512] + bb[t + 512]);
}

// ---------- 256x256 8-wave 8-phase GEMM (deep-cover staging, compiler fine-waits): ----------
// Chunk liveness per K-tile (reads P0: LDB(n0)+LDA(m0), P1: LDB(n1), P2: LDA(m1)):
//   A chunks {0,2} dead after P0; B chunks {0..3} dead after P1; A chunks {1,3} dead after P2.
// Stage slots: P1 -> A0,A2 ; P2 -> B0,B1 ; P3 -> A1,A3,B2,B3 (mirror P5/P6/P7 for odd tile).
// vmcnt(8) at P3/P7 drains exactly the 8 oldest loads (= the buffer consumed next).
// NO sched_barrier / explicit lgkmcnt: ds_read->MFMA deps are compiler-modeled, so hipcc
// emits fine-grained lgkmcnt(N) letting each MFMA start as soon as its frags land (m97/m141).
// EPI 0: +bias -> bf16 (qkv)
// EPI 1: +bias, window-reverse+unshift scatter, +resid(x) -> fp32 xr (proj)
// EPI 2: +bias, exact gelu -> bf16 (fc1)
// EPI 3: +bias, +resid(xr) -> fp32 out (fc2)
template <int EPI>
__global__ __launch_bounds__(512, 2) void gemm256(
    const unsigned short* __restrict__ A, const unsigned short* __restrict__ BT,
    const float* __restrict__ bias, float* __restrict__ outF,
    unsigned short* __restrict__ outB, const float* __restrict__ resid,
    int M, int N, int K, int NT) {
  // per K-tile buffer: 256 rows x 64 K bf16, row stride 128B, 16B-granule swizzled by row&7
  // even K-tiles -> buf 0, odd -> buf 1 (static parity, no runtime indexing)
  __shared__ __align__(16) unsigned short sA[2][256 * 64];
  __shared__ __align__(16) unsigned short sB[2][256 * 64];

  const int tid = threadIdx.x;
  const int lane = tid & 63, wv = tid >> 6;
  const int wr = wv >> 2, wc = wv & 3;        // 2 (M) x 4 (N) wave grid
  const int fr = lane & 15, q4 = (lane >> 4) << 2;

  // bijective XCD swizzle (grid % 8 == 0 for all our launches)
  const int nwg = gridDim.x;
  const int orig = blockIdx.x;
  const int swz = (orig & 7) * (nwg >> 3) + (orig >> 3);
  const int mt = swz / NT, nt = swz - mt * NT;
  const int m0 = mt << 8, n0 = nt << 8;

  const size_t K2 = (size_t)K * 2;

  // staging: linear LDS dest (wave-uniform base + lane*16); pre-swizzled global src
  const int srow = tid >> 3;                  // row within 64-row chunk
  const int sg = tid & 7;                     // dest granule
  const int sgs = ((sg ^ (srow & 7)) << 4);   // swizzled source byte offset
  const char* pA = (const char*)A + (size_t)(m0 + srow) * K2 + sgs;
  const char* pB = (const char*)BT + (size_t)(n0 + srow) * K2 + sgs;
  char* sdA = (char*)&sA[0][0] + (wv << 10);
  char* sdB = (char*)&sB[0][0] + (wv << 10);

  // swizzled ds_read granule byte offsets per k-slice
  const int g0 = (((lane >> 4) ^ (fr & 7)) << 4);
  const int g1 = (((4 + (lane >> 4)) ^ (fr & 7)) << 4);
  const int arow = (wr << 7) + fr;
  const int brow = (wc << 6) + fr;

  f32x4 acc[8][4];
  #pragma unroll
  for (int i = 0; i < 8; ++i)
    #pragma unroll
    for (int j = 0; j < 4; ++j) acc[i][j] = (f32x4){0.f, 0.f, 0.f, 0.f};

  bf16x8 af[4][2];        // A frags, one M-half at a time
  bf16x8 bbv[2][2][2];    // B frags, both N-halves live
  const int KT = K >> 6;
  const int NI = KT >> 1;  // 2 K-tiles per iteration (KT even, >=4 for all our shapes)

#define BARR __builtin_amdgcn_s_barrier()
#define VM8 asm volatile("s_waitcnt vmcnt(8)" ::: "memory")
#define VM0 asm volatile("s_waitcnt vmcnt(0)" ::: "memory")

#define LDA(CB, mh)                                                          \
  {                                                                          \
    const char* ba = ((const char*)&sA[0][0]) + (CB)*32768;                  \
    _Pragma("unroll") for (int fm = 0; fm < 4; ++fm) {                       \
      const int r = arow + (mh)*64 + fm * 16;                                \
      af[fm][0] = *(const bf16x8*)(ba + r * 128 + g0);                       \
      af[fm][1] = *(const bf16x8*)(ba + r * 128 + g1);                       \
    }                                                                        \
  }
#define LDB(CB, nh)                                                          \
  {                                                                          \
    const char* ba = ((const char*)&sB[0][0]) + (CB)*32768;                  \
    _Pragma("unroll") for (int fn = 0; fn < 2; ++fn) {                       \
      const int r = brow + (nh)*32 + fn * 16;                                \
      bbv[nh][fn][0] = *(const bf16x8*)(ba + r * 128 + g0);                  \
      bbv[nh][fn][1] = *(const bf16x8*)(ba + r * 128 + g1);                  \
    }                                                                        \
  }
#define STGA(CB, tt, j)                                                      \
  gld16(pA + (size_t)((j)*64) * K2 + ((size_t)(tt) << 7),                    \
        sdA + (CB)*32768 + (j)*8192);
#define STGB(CB, tt, j)                                                      \
  gld16(pB + (size_t)((j)*64) * K2 + ((size_t)(tt) << 7),                    \
        sdB + (CB)*32768 + (j)*8192);
#define MMAQ(mh, nh)                                                         \
  _Pragma("unroll") for (int fm = 0; fm < 4; ++fm)                           \
      _Pragma("unroll") for (int fn = 0; fn < 2; ++fn) {                     \
    f32x4* ac = &acc[(mh)*4 + fm][(nh)*2 + fn];                              \
    *ac = __builtin_amdgcn_mfma_f32_16x16x32_bf16(af[fm][0], bbv[nh][fn][0], \
                                                  *ac, 0, 0, 0);             \
    *ac = __builtin_amdgcn_mfma_f32_16x16x32_bf16(af[fm][1], bbv[nh][fn][1], \
                                                  *ac, 0, 0, 0);             \
  }
#define OPEN  BARR; __builtin_amdgcn_s_setprio(1)
#define CLOSE __builtin_amdgcn_s_setprio(0)

  // prologue: stage tile0 (buf0) fully, then tile1 (buf1) fully; wait buf0 only
  #pragma unroll
  for (int j = 0; j < 4; ++j) { STGA(0, 0, j); STGB(0, 0, j); }
  #pragma unroll
  for (int j = 0; j < 4; ++j) { STGA(1, 1, j); STGB(1, 1, j); }
  VM8;   // buf0's 8 loads landed; buf1's 8 still in flight
  BARR;

  for (int i = 0; i < NI; ++i) {
    const int s2 = 2 * i + 2, s3 = 2 * i + 3;
    const bool gl = (i + 1 < NI);
    // ---- K-tile 2i (buf0) ----
    // P0 (12 ds_reads; no staging)
    LDB(0, 0) LDA(0, 0)
    OPEN; MMAQ(0, 0); CLOSE; BARR;
    // P1: A chunks 0,2 of buf0 dead (fully read at P0) -> stage next tile's A0,A2
    LDB(0, 1)
    if (gl) { STGA(0, s2, 0); STGA(0, s2, 2); }
    OPEN; MMAQ(0, 1); CLOSE; BARR;
    // P2: all B chunks of buf0 dead (read at P0+P1) -> stage B0,B1
    LDA(0, 1)
    if (gl) { STGB(0, s2, 0); STGB(0, s2, 1); }
    OPEN; MMAQ(1, 1); CLOSE; BARR;
    // P3: A chunks 1,3 dead (read at P2) -> stage A1,A3 + B2,B3
    if (gl) { STGA(0, s2, 1); STGA(0, s2, 3); STGB(0, s2, 2); STGB(0, s2, 3); }
    OPEN; MMAQ(1, 0); CLOSE;
    if (gl) { VM8; } else { VM0; }   // drain 8 oldest (= buf1's tile); keep buf0-next in flight
    BARR;
    // ---- K-tile 2i+1 (buf1) ----
    // P4
    LDB(1, 0) LDA(1, 0)
    OPEN; MMAQ(0, 0); CLOSE; BARR;
    // P5: buf1 A chunks 0,2 dead -> stage A0,A2
    LDB(1, 1)
    if (gl) { STGA(1, s3, 0); STGA(1, s3, 2); }
    OPEN; MMAQ(0, 1); CLOSE; BARR;
    // P6: buf1 B chunks dead -> stage B0,B1
    LDA(1, 1)
    if (gl) { STGB(1, s3, 0); STGB(1, s3, 1); }
    OPEN; MMAQ(1, 1); CLOSE; BARR;
    // P7: buf1 A chunks 1,3 dead -> stage A1,A3 + B2,B3
    if (gl) { STGA(1, s3, 1); STGA(1, s3, 3); STGB(1, s3, 2); STGB(1, s3, 3); }
    OPEN; MMAQ(1, 0); CLOSE;
    if (gl) { VM8; }                 // drain 8 oldest (= buf0-next's tile)
    BARR;
  }
#undef BARR
#undef VM8
#undef VM0
#undef LDA
#undef LDB
#undef STGA
#undef STGB
#undef MMAQ
#undef OPEN
#undef CLOSE

  #pragma unroll
  for (int ai = 0; ai < 8; ++ai) {
    #pragma unroll
    for (int bj = 0; bj < 4; ++bj) {
      const int col = n0 + (wc << 6) + bj * 16 + fr;
      const float bc = bias[col];
      #pragma unroll
      for (int i = 0; i < 4; ++i) {
        const int row = m0 + (wr << 7) + ai * 16 + q4 + i;
        float v = acc[ai][bj][i] + bc;
        if (EPI == 0) {
          outB[(size_t)row * N + col] = f2bf(v);
        } else if (EPI == 1) {
          int b = row >> 7, wid = (row >> 4) & 7, tok = row & 15;
          int oh = (((wid >> 2) << 2) + (tok >> 2) + 2) & 7;
          int ow = (((wid & 3) << 2) + (tok & 3) + 2) & 15;
          size_t di = ((size_t)(b << 7) + oh * 16 + ow) * 768 + col;
          outF[di] = v + resid[di];
        } else if (EPI == 2) {
          float g = 0.5f * v * (1.0f + erff(v * 0.70710678118f));
          outB[(size_t)row * N + col] = f2bf(g);
        } else {
          size_t di = (size_t)row * N + col;
          outF[di] = v + resid[di];
        }
      }
    }
  }
}

// ---------- window attention: one wave per (window, head) ----------
__global__ __launch_bounds__(64) void attn_win(const unsigned short* __restrict__ qkv,
                                               const float* __restrict__ rel_table,
                                               unsigned short* __restrict__ o) {
  __shared__ __align__(16) unsigned short q_s[16 * 64];
  __shared__ __align__(16) unsigned short k_s[16 * 64];
  __shared__ __align__(16) unsigned short vt_s[64 * 32];  // [d][m], m padded to 32
  __shared__ __align__(16) unsigned short p_s[16 * 32];   // [n][m], m padded to 32
  const int bid = blockIdx.x;
  const int win = bid / 12;
  const int head = bid - win * 12;
  const int wid = win & 7;
  const int lane = threadIdx.x;
  const unsigned short* gq =
      qkv + (size_t)win * 16 * 2304 + head * 64 + (size_t)(lane >> 2) * 2304 + ((lane & 3) << 4);
  const int t = lane >> 2, d0 = (lane & 3) << 4;
  *(uint4v*)&q_s[t * 64 + d0]     = *(const uint4v*)(gq);
  *(uint4v*)&q_s[t * 64 + d0 + 8] = *(const uint4v*)(gq + 8);
  *(uint4v*)&k_s[t * 64 + d0]     = *(const uint4v*)(gq + 768);
  *(uint4v*)&k_s[t * 64 + d0 + 8] = *(const uint4v*)(gq + 776);
  unsigned short vv[16];
  *(uint4v*)&vv[0] = *(const uint4v*)(gq + 1536);
  *(uint4v*)&vv[8] = *(const uint4v*)(gq + 1544);
  #pragma unroll
  for (int e = 0; e < 16; ++e) vt_s[(d0 + e) * 32 + t] = vv[e];
  #pragma unroll
  for (int e = 0; e < 16; ++e) vt_s[lane * 32 + 16 + e] = 0;  // K-pad of V
  if (lane < 16) {
    #pragma unroll
    for (int e = 0; e < 16; ++e) p_s[lane * 32 + 16 + e] = 0;  // K-pad of P
  }
  __syncthreads();

  const int fr = lane & 15, kg = (lane >> 4) << 3;
  bf16x8 qa0 = *(const bf16x8*)&q_s[fr * 64 + kg];
  bf16x8 qa1 = *(const bf16x8*)&q_s[fr * 64 + 32 + kg];
  bf16x8 ka0 = *(const bf16x8*)&k_s[fr * 64 + kg];
  bf16x8 ka1 = *(const bf16x8*)&k_s[fr * 64 + 32 + kg];
  f32x4 s = (f32x4){0.f, 0.f, 0.f, 0.f};
  s = __builtin_amdgcn_mfma_f32_16x16x32_bf16(qa0, ka0, s, 0, 0, 0);
  s = __builtin_amdgcn_mfma_f32_16x16x32_bf16(qa1, ka1, s, 0, 0, 0);
  // S[n][m]: n = (lane>>4)*4 + i, m = fr

  const int wh = wid >> 2, wwc = wid & 3;
  const int rj = fr >> 2, cj = fr & 3;
  const int rowm = wh * 4 + rj, colm = wwc * 4 + cj;
  const int rgm = (rowm < 4 ? 0 : (rowm < 6 ? 1 : 2)) * 3 +
                  (colm < 12 ? 0 : (colm < 14 ? 1 : 2));
  float p[4];
  #pragma unroll
  for (int i = 0; i < 4; ++i) {
    int n = ((lane >> 4) << 2) + i;
    int ri = n >> 2, ci = n & 3;
    int rown = wh * 4 + ri, coln = wwc * 4 + ci;
    int rgn = (rown < 4 ? 0 : (rown < 6 ? 1 : 2)) * 3 +
              (coln < 12 ? 0 : (coln < 14 ? 1 : 2));
    float bias = rel_table[(size_t)((ri - rj + 3) * 7 + (ci - cj + 3)) * 12 + head];
    p[i] = s[i] * 0.125f + bias + (rgn != rgm ? -100.0f : 0.0f);
  }
  float mx[4] = {p[0], p[1], p[2], p[3]};
  #pragma unroll
  for (int off = 8; off > 0; off >>= 1)
    #pragma unroll
    for (int i = 0; i < 4; ++i) mx[i] = fmaxf(mx[i], __shfl_xor(mx[i], off, 64));
  float sm[4];
  #pragma unroll
  for (int i = 0; i < 4; ++i) { p[i] = __expf(p[i] - mx[i]); sm[i] = p[i]; }
  #pragma unroll
  for (int off = 8; off > 0; off >>= 1)
    #pragma unroll
    for (int i = 0; i < 4; ++i) sm[i] += __shfl_xor(sm[i], off, 64);
  #pragma unroll
  for (int i = 0; i < 4; ++i)
    p_s[(((lane >> 4) << 2) + i) * 32 + fr] = f2bf(p[i] / sm[i]);
  __syncthreads();

  bf16x8 pa = *(const bf16x8*)&p_s[fr * 32 + kg];
  const f32x4 oz = (f32x4){0.f, 0.f, 0.f, 0.f};
  #pragma unroll
  for (int c = 0; c < 4; ++c) {
    bf16x8 vb = *(const bf16x8*)&vt_s[(c * 16 + fr) * 32 + kg];
    f32x4 oa = __builtin_amdgcn_mfma_f32_16x16x32_bf16(pa, vb, oz, 0, 0, 0);
    #pragma unroll
    for (int i = 0; i < 4; ++i) {
      int n = ((lane >> 4) << 2) + i;
      o[((size_t)win * 16 + n) * 768 + head * 64 + c * 16 + fr] = f2bf(oa[i]);
    }
  }
}

extern "C" void kernel_launch(void* const* d_in, const int* in_sizes, int n_in,
                              void* d_out, int out_size, void* d_ws, size_t ws_size,
                              hipStream_t stream) {
  const float* x      = (const float*)d_in[0];
  const float* ln1_g  = (const float*)d_in[1];
  const float* ln1_b  = (const float*)d_in[2];
  const float* qkv_w  = (const float*)d_in[3];
  const float* qkv_b  = (const float*)d_in[4];
  const float* proj_w = (const float*)d_in[5];
  const float* proj_b = (const float*)d_in[6];
  const float* rel_t  = (const float*)d_in[7];
  const float* ln2_g  = (const float*)d_in[8];
  const float* ln2_b  = (const float*)d_in[9];
  const float* fc1_w  = (const float*)d_in[10];
  const float* fc1_b  = (const float*)d_in[11];
  const float* fc2_w  = (const float*)d_in[12];
  const float* fc2_b  = (const float*)d_in[13];
  float* out = (float*)d_out;

  char* ws = (char*)d_ws;
  // region A (50,331,648 B): hw -> o -> y  (all [32768][768] bf16, sequential reuse)
  unsigned short* wsA = (unsigned short*)(ws);
  // region B: qkv bf16 [32768][2304]; later xr fp32 [32768][768]
  unsigned short* qkvb = (unsigned short*)(ws + 50331648);
  float* xr = (float*)(ws + 50331648);
  // region C: h1 bf16 [32768][1024]
  unsigned short* h1 = (unsigned short*)(ws + 201326592);
  // bf16 transposed weights
  unsigned short* qkv_wT = (unsigned short*)(ws + 268435456);  // [2304][768]
  unsigned short* proj_wT = (unsigned short*)(ws + 271974400); // [768][768]
  unsigned short* fc1_wT = (unsigned short*)(ws + 273154048);  // [1024][768]
  unsigned short* fc2_wT = (unsigned short*)(ws + 274726912);  // [768][1024]

  dim3 tb(32, 8);
  transpose_cast<<<dim3(2304 / 32, 768 / 32), tb, 0, stream>>>(qkv_w, qkv_wT, 768, 2304);
  transpose_cast<<<dim3(768 / 32, 768 / 32), tb, 0, stream>>>(proj_w, proj_wT, 768, 768);
  transpose_cast<<<dim3(1024 / 32, 768 / 32), tb, 0, stream>>>(fc1_w, fc1_wT, 768, 1024);
  transpose_cast<<<dim3(768 / 32, 1024 / 32), tb, 0, stream>>>(fc2_w, fc2_wT, 1024, 768);

  ln_kernel<0><<<32768, 256, 0, stream>>>(x, ln1_g, ln1_b, wsA);                 // hw
  gemm256<0><<<dim3(128 * 9), 512, 0, stream>>>(wsA, qkv_wT, qkv_b, nullptr, qkvb,
                                                nullptr, 32768, 2304, 768, 9);   // qkv
  attn_win<<<24576, 64, 0, stream>>>(qkvb, rel_t, wsA);                          // o
  gemm256<1><<<dim3(128 * 3), 512, 0, stream>>>(wsA, proj_wT, proj_b, xr, nullptr,
                                                x, 32768, 768, 768, 3);          // xr = x + proj(o)
  ln_kernel<1><<<32768, 256, 0, stream>>>(xr, ln2_g, ln2_b, wsA);                // y
  gemm256<2><<<dim3(128 * 4), 512, 0, stream>>>(wsA, fc1_wT, fc1_b, nullptr, h1,
                                                nullptr, 32768, 1024, 768, 4);   // h1 = gelu(...)
  gemm256<3><<<dim3(128 * 3), 512, 0, stream>>>(h1, fc2_wT, fc2_b, out, nullptr,
                                                xr, 32768, 768, 1024, 3);        // out = xr + fc2(h1)
}

// Round 7
// 512.994 us; speedup vs baseline: 1.2024x; 1.0597x over previous
//
#include <hip/hip_runtime.h>
#include <stdint.h>
#include <stddef.h>

typedef __attribute__((ext_vector_type(8))) short bf16x8;
typedef __attribute__((ext_vector_type(4))) float f32x4;
typedef __attribute__((ext_vector_type(4))) unsigned int uint4v;

static __device__ __forceinline__ unsigned short f2bf(float f) {
  unsigned int u = __builtin_bit_cast(unsigned int, f);
  unsigned int r = (u + 0x7FFFu + ((u >> 16) & 1u)) >> 16;
  return (unsigned short)r;
}
static __device__ __forceinline__ float bf2f(unsigned short h) {
  unsigned int u = ((unsigned int)h) << 16;
  return __builtin_bit_cast(float, u);
}

static __device__ __forceinline__ void gld16(const void* g, void* l) {
  __builtin_amdgcn_global_load_lds(
      (const __attribute__((address_space(1))) void*)g,
      (__attribute__((address_space(3))) void*)l, 16, 0, 0);
}

// ---------- weight transpose + cast: src [R][C] f32 -> dst [C][R] bf16 ----------
__global__ void transpose_cast(const float* __restrict__ src,
                               unsigned short* __restrict__ dst, int R, int C) {
  __shared__ float tile[32][33];
  int c0 = blockIdx.x * 32, r0 = blockIdx.y * 32;
  int tx = threadIdx.x, ty = threadIdx.y;  // (32, 8)
  #pragma unroll
  for (int i = 0; i < 32; i += 8)
    tile[ty + i][tx] = src[(size_t)(r0 + ty + i) * C + c0 + tx];
  __syncthreads();
  #pragma unroll
  for (int i = 0; i < 32; i += 8)
    dst[(size_t)(c0 + ty + i) * R + r0 + tx] = f2bf(tile[tx][ty + i]);
}

// ---------- block reduce ----------
static __device__ __forceinline__ float blksum256(float v, float* sb) {
  #pragma unroll
  for (int o = 32; o > 0; o >>= 1) v += __shfl_down(v, o, 64);
  int lane = threadIdx.x & 63, w = threadIdx.x >> 6;
  __syncthreads();
  if (lane == 0) sb[w] = v;
  __syncthreads();
  return sb[0] + sb[1] + sb[2] + sb[3];
}

// ---------- LayerNorm ----------
// MODE 0: fp32 input, write shifted/window-partitioned rows (ln1)
// MODE 2: bf16 input (xr), identity rows (ln2)
template <int MODE>
__global__ __launch_bounds__(256) void ln_kernel(const float* __restrict__ xf,
                                                 const unsigned short* __restrict__ xb,
                                                 const float* __restrict__ gg,
                                                 const float* __restrict__ bb,
                                                 unsigned short* __restrict__ out) {
  __shared__ float sb[4];
  const int d = blockIdx.x;  // dest row (window order for MODE 0)
  size_t srow;
  if (MODE == 0) {
    int b = d >> 7, wid = (d >> 4) & 7, tok = d & 15;
    int oh = (((wid >> 2) << 2) + (tok >> 2) + 2) & 7;
    int ow = (((wid & 3) << 2) + (tok & 3) + 2) & 15;
    srow = (size_t)(b << 7) + oh * 16 + ow;
  } else {
    srow = d;
  }
  const int t = threadIdx.x;
  float v0, v1, v2;
  if (MODE == 0) {
    const float* xr_ = xf + srow * 768;
    v0 = xr_[t]; v1 = xr_[t + 256]; v2 = xr_[t + 512];
  } else {
    const unsigned short* xr_ = xb + srow * 768;
    v0 = bf2f(xr_[t]); v1 = bf2f(xr_[t + 256]); v2 = bf2f(xr_[t + 512]);
  }
  float mean = blksum256(v0 + v1 + v2, sb) * (1.0f / 768.0f);
  float d0 = v0 - mean, d1 = v1 - mean, d2 = v2 - mean;
  float var = blksum256(d0 * d0 + d1 * d1 + d2 * d2, sb) * (1.0f / 768.0f);
  float rstd = rsqrtf(var + 1e-5f);
  size_t o = (size_t)d * 768;
  out[o + t]       = f2bf(d0 * rstd * gg[t] + bb[t]);
  out[o + t + 256] = f2bf(d1 * rstd * gg[t + 256] + bb[t + 256]);
  out[o + t + 512] = f2bf(d2 * rstd * gg[t + 512] + bb[t + 512]);
}

// ---------- 256x256 8-wave 8-phase GEMM (m201-exact staging rhythm) ----------
// Chunk liveness per K-tile: A{0,2} dead after P0; B{0..3} dead after P1; A{1,3} after P2.
// Staging: 2 gld16/phase, every phase; tile's A1,A3 wrap into next iter's P0.
//   P0: buf1(2i+1) A1,A3 (uncond)   P4: s2 A1,A3
//   P1: s2 A0,A2                    P5: s3 A0,A2
//   P2: s2 B0,B1                    P6: s3 B0,B1
//   P3: s2 B2,B3 + vmcnt(6)         P7: s3 B2,B3 + vmcnt(6)
// At P3-end exactly 6 younger loads in flight -> vmcnt(6) drains the 8 of buf1(2i+1). ✓
// EPI 0: +bias -> bf16 (qkv)
// EPI 1: +bias, window-reverse+unshift scatter, +resid(x fp32) -> bf16 xr (proj)
// EPI 2: +bias, exact gelu -> bf16 (fc1)
// EPI 3: +bias, +residB(xr bf16) -> fp32 out (fc2)
template <int EPI>
__global__ __launch_bounds__(512, 2) void gemm256(
    const unsigned short* __restrict__ A, const unsigned short* __restrict__ BT,
    const float* __restrict__ bias, float* __restrict__ outF,
    unsigned short* __restrict__ outB, const float* __restrict__ resid,
    const unsigned short* __restrict__ residB,
    int M, int N, int K, int NT) {
  __shared__ __align__(16) unsigned short sA[2][256 * 64];
  __shared__ __align__(16) unsigned short sB[2][256 * 64];

  const int tid = threadIdx.x;
  const int lane = tid & 63, wv = tid >> 6;
  const int wr = wv >> 2, wc = wv & 3;        // 2 (M) x 4 (N) wave grid
  const int fr = lane & 15, q4 = (lane >> 4) << 2;

  // bijective XCD swizzle (grid % 8 == 0 for all our launches)
  const int nwg = gridDim.x;
  const int orig = blockIdx.x;
  const int swz = (orig & 7) * (nwg >> 3) + (orig >> 3);
  const int mt = swz / NT, nt = swz - mt * NT;
  const int m0 = mt << 8, n0 = nt << 8;

  const size_t K2 = (size_t)K * 2;

  // staging: linear LDS dest (wave-uniform base + lane*16); pre-swizzled global src
  const int srow = tid >> 3;                  // row within 64-row chunk
  const int sg = tid & 7;                     // dest granule
  const int sgs = ((sg ^ (srow & 7)) << 4);   // swizzled source byte offset
  const char* pA = (const char*)A + (size_t)(m0 + srow) * K2 + sgs;
  const char* pB = (const char*)BT + (size_t)(n0 + srow) * K2 + sgs;
  char* sdA = (char*)&sA[0][0] + (wv << 10);
  char* sdB = (char*)&sB[0][0] + (wv << 10);

  // swizzled ds_read granule byte offsets per k-slice
  const int g0 = (((lane >> 4) ^ (fr & 7)) << 4);
  const int g1 = (((4 + (lane >> 4)) ^ (fr & 7)) << 4);
  const int arow = (wr << 7) + fr;
  const int brow = (wc << 6) + fr;

  f32x4 acc[8][4];
  #pragma unroll
  for (int i = 0; i < 8; ++i)
    #pragma unroll
    for (int j = 0; j < 4; ++j) acc[i][j] = (f32x4){0.f, 0.f, 0.f, 0.f};

  bf16x8 af[4][2];        // A frags, one M-half at a time
  bf16x8 bbv[2][2][2];    // B frags, both N-halves live
  const int KT = K >> 6;
  const int NI = KT >> 1;  // 2 K-tiles per iteration (KT even, >=2)

#define BARR __builtin_amdgcn_s_barrier()
#define LGKM0 asm volatile("s_waitcnt lgkmcnt(0)" ::: "memory")
#define VM6 asm volatile("s_waitcnt vmcnt(6)" ::: "memory")
#define VM0 asm volatile("s_waitcnt vmcnt(0)" ::: "memory")

#define LDA(CB, mh)                                                          \
  {                                                                          \
    const char* ba = ((const char*)&sA[0][0]) + (CB)*32768;                  \
    _Pragma("unroll") for (int fm = 0; fm < 4; ++fm) {                       \
      const int r = arow + (mh)*64 + fm * 16;                                \
      af[fm][0] = *(const bf16x8*)(ba + r * 128 + g0);                       \
      af[fm][1] = *(const bf16x8*)(ba + r * 128 + g1);                       \
    }                                                                        \
  }
#define LDB(CB, nh)                                                          \
  {                                                                          \
    const char* ba = ((const char*)&sB[0][0]) + (CB)*32768;                  \
    _Pragma("unroll") for (int fn = 0; fn < 2; ++fn) {                       \
      const int r = brow + (nh)*32 + fn * 16;                                \
      bbv[nh][fn][0] = *(const bf16x8*)(ba + r * 128 + g0);                  \
      bbv[nh][fn][1] = *(const bf16x8*)(ba + r * 128 + g1);                  \
    }                                                                        \
  }
#define STGA(CB, tt, j)                                                      \
  gld16(pA + (size_t)((j)*64) * K2 + ((size_t)(tt) << 7),                    \
        sdA + (CB)*32768 + (j)*8192);
#define STGB(CB, tt, j)                                                      \
  gld16(pB + (size_t)((j)*64) * K2 + ((size_t)(tt) << 7),                    \
        sdB + (CB)*32768 + (j)*8192);
#define MMAQ(mh, nh)                                                         \
  _Pragma("unroll") for (int fm = 0; fm < 4; ++fm)                           \
      _Pragma("unroll") for (int fn = 0; fn < 2; ++fn) {                     \
    f32x4* ac = &acc[(mh)*4 + fm][(nh)*2 + fn];                              \
    *ac = __builtin_amdgcn_mfma_f32_16x16x32_bf16(af[fm][0], bbv[nh][fn][0], \
                                                  *ac, 0, 0, 0);             \
    *ac = __builtin_amdgcn_mfma_f32_16x16x32_bf16(af[fm][1], bbv[nh][fn][1], \
                                                  *ac, 0, 0, 0);             \
  }
#define OPEN  BARR; LGKM0; __builtin_amdgcn_s_setprio(1)
#define CLOSE __builtin_amdgcn_s_setprio(0)

  // prologue: tile0 all 8 chunks, then tile1's A0,A2,B0..B3 (6); tile1 A1,A3 wrap to iter0 P0
  #pragma unroll
  for (int j = 0; j < 4; ++j) { STGA(0, 0, j); STGB(0, 0, j); }
  STGA(1, 1, 0); STGA(1, 1, 2);
  STGB(1, 1, 0); STGB(1, 1, 1); STGB(1, 1, 2); STGB(1, 1, 3);
  VM6;   // tile0's 8 landed; tile1's 6 may fly
  BARR;

  for (int i = 0; i < NI; ++i) {
    const int s1 = 2 * i + 1, s2 = 2 * i + 2, s3 = 2 * i + 3;
    const bool gl = (i + 1 < NI);
    // ---- K-tile 2i (buf0) ----
    // P0: finish buf1's tile s1 (A1,A3; consumed this iter at P6)
    LDB(0, 0) LDA(0, 0)
    STGA(1, s1, 1); STGA(1, s1, 3);
    OPEN; MMAQ(0, 0); CLOSE; BARR;
    // P1
    LDB(0, 1)
    if (gl) { STGA(0, s2, 0); STGA(0, s2, 2); }
    OPEN; MMAQ(0, 1); CLOSE; BARR;
    // P2
    LDA(0, 1)
    if (gl) { STGB(0, s2, 0); STGB(0, s2, 1); }
    OPEN; MMAQ(1, 1); CLOSE; BARR;
    // P3
    if (gl) { STGB(0, s2, 2); STGB(0, s2, 3); }
    OPEN; MMAQ(1, 0); CLOSE;
    if (gl) { VM6; } else { VM0; }   // drain tile s1's 8 (oldest)
    BARR;
    // ---- K-tile 2i+1 (buf1) ----
    // P4
    LDB(1, 0) LDA(1, 0)
    if (gl) { STGA(0, s2, 1); STGA(0, s2, 3); }
    OPEN; MMAQ(0, 0); CLOSE; BARR;
    // P5
    LDB(1, 1)
    if (gl) { STGA(1, s3, 0); STGA(1, s3, 2); }
    OPEN; MMAQ(0, 1); CLOSE; BARR;
    // P6
    LDA(1, 1)
    if (gl) { STGB(1, s3, 0); STGB(1, s3, 1); }
    OPEN; MMAQ(1, 1); CLOSE; BARR;
    // P7
    if (gl) { STGB(1, s3, 2); STGB(1, s3, 3); }
    OPEN; MMAQ(1, 0); CLOSE;
    if (gl) { VM6; }                 // drain tile s2's 8 (oldest)
    BARR;
  }
#undef BARR
#undef LGKM0
#undef VM6
#undef VM0
#undef LDA
#undef LDB
#undef STGA
#undef STGB
#undef MMAQ
#undef OPEN
#undef CLOSE

  #pragma unroll
  for (int ai = 0; ai < 8; ++ai) {
    #pragma unroll
    for (int bj = 0; bj < 4; ++bj) {
      const int col = n0 + (wc << 6) + bj * 16 + fr;
      const float bc = bias[col];
      #pragma unroll
      for (int i = 0; i < 4; ++i) {
        const int row = m0 + (wr << 7) + ai * 16 + q4 + i;
        float v = acc[ai][bj][i] + bc;
        if (EPI == 0) {
          outB[(size_t)row * N + col] = f2bf(v);
        } else if (EPI == 1) {
          int b = row >> 7, wid = (row >> 4) & 7, tok = row & 15;
          int oh = (((wid >> 2) << 2) + (tok >> 2) + 2) & 7;
          int ow = (((wid & 3) << 2) + (tok & 3) + 2) & 15;
          size_t di = ((size_t)(b << 7) + oh * 16 + ow) * 768 + col;
          outB[di] = f2bf(v + resid[di]);
        } else if (EPI == 2) {
          float g = 0.5f * v * (1.0f + erff(v * 0.70710678118f));
          outB[(size_t)row * N + col] = f2bf(g);
        } else {
          size_t di = (size_t)row * N + col;
          outF[di] = v + bf2f(residB[di]);
        }
      }
    }
  }
}

// ---------- window attention: one wave per (window, head) ----------
__global__ __launch_bounds__(64) void attn_win(const unsigned short* __restrict__ qkv,
                                               const float* __restrict__ rel_table,
                                               unsigned short* __restrict__ o) {
  __shared__ __align__(16) unsigned short q_s[16 * 64];
  __shared__ __align__(16) unsigned short k_s[16 * 64];
  __shared__ __align__(16) unsigned short vt_s[64 * 32];  // [d][m], m padded to 32
  __shared__ __align__(16) unsigned short p_s[16 * 32];   // [n][m], m padded to 32
  const int bid = blockIdx.x;
  const int win = bid / 12;
  const int head = bid - win * 12;
  const int wid = win & 7;
  const int lane = threadIdx.x;
  const unsigned short* gq =
      qkv + (size_t)win * 16 * 2304 + head * 64 + (size_t)(lane >> 2) * 2304 + ((lane & 3) << 4);
  const int t = lane >> 2, d0 = (lane & 3) << 4;
  *(uint4v*)&q_s[t * 64 + d0]     = *(const uint4v*)(gq);
  *(uint4v*)&q_s[t * 64 + d0 + 8] = *(const uint4v*)(gq + 8);
  *(uint4v*)&k_s[t * 64 + d0]     = *(const uint4v*)(gq + 768);
  *(uint4v*)&k_s[t * 64 + d0 + 8] = *(const uint4v*)(gq + 776);
  unsigned short vv[16];
  *(uint4v*)&vv[0] = *(const uint4v*)(gq + 1536);
  *(uint4v*)&vv[8] = *(const uint4v*)(gq + 1544);
  #pragma unroll
  for (int e = 0; e < 16; ++e) vt_s[(d0 + e) * 32 + t] = vv[e];
  #pragma unroll
  for (int e = 0; e < 16; ++e) vt_s[lane * 32 + 16 + e] = 0;  // K-pad of V
  if (lane < 16) {
    #pragma unroll
    for (int e = 0; e < 16; ++e) p_s[lane * 32 + 16 + e] = 0;  // K-pad of P
  }
  __syncthreads();

  const int fr = lane & 15, kg = (lane >> 4) << 3;
  bf16x8 qa0 = *(const bf16x8*)&q_s[fr * 64 + kg];
  bf16x8 qa1 = *(const bf16x8*)&q_s[fr * 64 + 32 + kg];
  bf16x8 ka0 = *(const bf16x8*)&k_s[fr * 64 + kg];
  bf16x8 ka1 = *(const bf16x8*)&k_s[fr * 64 + 32 + kg];
  f32x4 s = (f32x4){0.f, 0.f, 0.f, 0.f};
  s = __builtin_amdgcn_mfma_f32_16x16x32_bf16(qa0, ka0, s, 0, 0, 0);
  s = __builtin_amdgcn_mfma_f32_16x16x32_bf16(qa1, ka1, s, 0, 0, 0);
  // S[n][m]: n = (lane>>4)*4 + i, m = fr

  const int wh = wid >> 2, wwc = wid & 3;
  const int rj = fr >> 2, cj = fr & 3;
  const int rowm = wh * 4 + rj, colm = wwc * 4 + cj;
  const int rgm = (rowm < 4 ? 0 : (rowm < 6 ? 1 : 2)) * 3 +
                  (colm < 12 ? 0 : (colm < 14 ? 1 : 2));
  float p[4];
  #pragma unroll
  for (int i = 0; i < 4; ++i) {
    int n = ((lane >> 4) << 2) + i;
    int ri = n >> 2, ci = n & 3;
    int rown = wh * 4 + ri, coln = wwc * 4 + ci;
    int rgn = (rown < 4 ? 0 : (rown < 6 ? 1 : 2)) * 3 +
              (coln < 12 ? 0 : (coln < 14 ? 1 : 2));
    float bias = rel_table[(size_t)((ri - rj + 3) * 7 + (ci - cj + 3)) * 12 + head];
    p[i] = s[i] * 0.125f + bias + (rgn != rgm ? -100.0f : 0.0f);
  }
  float mx[4] = {p[0], p[1], p[2], p[3]};
  #pragma unroll
  for (int off = 8; off > 0; off >>= 1)
    #pragma unroll
    for (int i = 0; i < 4; ++i) mx[i] = fmaxf(mx[i], __shfl_xor(mx[i], off, 64));
  float sm[4];
  #pragma unroll
  for (int i = 0; i < 4; ++i) { p[i] = __expf(p[i] - mx[i]); sm[i] = p[i]; }
  #pragma unroll
  for (int off = 8; off > 0; off >>= 1)
    #pragma unroll
    for (int i = 0; i < 4; ++i) sm[i] += __shfl_xor(sm[i], off, 64);
  #pragma unroll
  for (int i = 0; i < 4; ++i)
    p_s[(((lane >> 4) << 2) + i) * 32 + fr] = f2bf(p[i] / sm[i]);
  __syncthreads();

  bf16x8 pa = *(const bf16x8*)&p_s[fr * 32 + kg];
  const f32x4 oz = (f32x4){0.f, 0.f, 0.f, 0.f};
  #pragma unroll
  for (int c = 0; c < 4; ++c) {
    bf16x8 vb = *(const bf16x8*)&vt_s[(c * 16 + fr) * 32 + kg];
    f32x4 oa = __builtin_amdgcn_mfma_f32_16x16x32_bf16(pa, vb, oz, 0, 0, 0);
    #pragma unroll
    for (int i = 0; i < 4; ++i) {
      int n = ((lane >> 4) << 2) + i;
      o[((size_t)win * 16 + n) * 768 + head * 64 + c * 16 + fr] = f2bf(oa[i]);
    }
  }
}

extern "C" void kernel_launch(void* const* d_in, const int* in_sizes, int n_in,
                              void* d_out, int out_size, void* d_ws, size_t ws_size,
                              hipStream_t stream) {
  const float* x      = (const float*)d_in[0];
  const float* ln1_g  = (const float*)d_in[1];
  const float* ln1_b  = (const float*)d_in[2];
  const float* qkv_w  = (const float*)d_in[3];
  const float* qkv_b  = (const float*)d_in[4];
  const float* proj_w = (const float*)d_in[5];
  const float* proj_b = (const float*)d_in[6];
  const float* rel_t  = (const float*)d_in[7];
  const float* ln2_g  = (const float*)d_in[8];
  const float* ln2_b  = (const float*)d_in[9];
  const float* fc1_w  = (const float*)d_in[10];
  const float* fc1_b  = (const float*)d_in[11];
  const float* fc2_w  = (const float*)d_in[12];
  const float* fc2_b  = (const float*)d_in[13];
  float* out = (float*)d_out;

  char* ws = (char*)d_ws;
  // region A (50,331,648 B): hw -> o -> y  (all [32768][768] bf16, sequential reuse)
  unsigned short* wsA = (unsigned short*)(ws);
  // region B: qkv bf16 [32768][2304]; later xr bf16 [32768][768]
  unsigned short* qkvb = (unsigned short*)(ws + 50331648);
  unsigned short* xr16 = (unsigned short*)(ws + 50331648);
  // region C: h1 bf16 [32768][1024]
  unsigned short* h1 = (unsigned short*)(ws + 201326592);
  // bf16 transposed weights
  unsigned short* qkv_wT = (unsigned short*)(ws + 268435456);  // [2304][768]
  unsigned short* proj_wT = (unsigned short*)(ws + 271974400); // [768][768]
  unsigned short* fc1_wT = (unsigned short*)(ws + 273154048);  // [1024][768]
  unsigned short* fc2_wT = (unsigned short*)(ws + 274726912);  // [768][1024]

  dim3 tb(32, 8);
  transpose_cast<<<dim3(2304 / 32, 768 / 32), tb, 0, stream>>>(qkv_w, qkv_wT, 768, 2304);
  transpose_cast<<<dim3(768 / 32, 768 / 32), tb, 0, stream>>>(proj_w, proj_wT, 768, 768);
  transpose_cast<<<dim3(1024 / 32, 768 / 32), tb, 0, stream>>>(fc1_w, fc1_wT, 768, 1024);
  transpose_cast<<<dim3(768 / 32, 1024 / 32), tb, 0, stream>>>(fc2_w, fc2_wT, 1024, 768);

  ln_kernel<0><<<32768, 256, 0, stream>>>(x, nullptr, ln1_g, ln1_b, wsA);        // hw
  gemm256<0><<<dim3(128 * 9), 512, 0, stream>>>(wsA, qkv_wT, qkv_b, nullptr, qkvb,
                                                nullptr, nullptr,
                                                32768, 2304, 768, 9);            // qkv
  attn_win<<<24576, 64, 0, stream>>>(qkvb, rel_t, wsA);                          // o
  gemm256<1><<<dim3(128 * 3), 512, 0, stream>>>(wsA, proj_wT, proj_b, nullptr, xr16,
                                                x, nullptr,
                                                32768, 768, 768, 3);             // xr16 = bf16(x + proj(o))
  ln_kernel<2><<<32768, 256, 0, stream>>>(nullptr, xr16, ln2_g, ln2_b, wsA);     // y
  gemm256<2><<<dim3(128 * 4), 512, 0, stream>>>(wsA, fc1_wT, fc1_b, nullptr, h1,
                                                nullptr, nullptr,
                                                32768, 1024, 768, 4);            // h1 = gelu(...)
  gemm256<3><<<dim3(128 * 3), 512, 0, stream>>>(h1, fc2_wT, fc2_b, out, nullptr,
                                                nullptr, xr16,
                                                32768, 768, 1024, 3);            // out = xr + fc2(h1)
}